// Round 10
// baseline (393.071 us; speedup 1.0000x reference)
//
#include <hip/hip_runtime.h>
#include <math.h>

#define EPSF 1e-5f

typedef short bf16x8 __attribute__((ext_vector_type(8)));
typedef float f32x4 __attribute__((ext_vector_type(4)));

static __device__ __forceinline__ unsigned short f2bf(float x) {
  unsigned u = __float_as_uint(x);
  unsigned r = (u + 0x7FFFu + ((u >> 16) & 1u)) >> 16;
  return (unsigned short)r;
}

union BU { uint4 u; bf16x8 v; };

// async global->LDS, 16B/lane; LDS dest = wave-uniform base + lane*16.
static __device__ __forceinline__ void gload16(const void* g, void* l) {
  __builtin_amdgcn_global_load_lds(
      (const __attribute__((address_space(1))) unsigned int*)g,
      (__attribute__((address_space(3))) unsigned int*)l, 16, 0, 0);
}

// ---------------- K1: Pdst[n][128] = x[n] @ [Wf(0:64)|Ws(0:64)] + bias -------
__global__ __launch_bounds__(256) void node_gemm(
    const float* __restrict__ x, const float* __restrict__ Wf,
    const float* __restrict__ bf, const float* __restrict__ Ws,
    const float* __restrict__ bs, float* __restrict__ Pdst, int N) {
  const int lane = threadIdx.x & 63;
  const int w = threadIdx.x >> 6;
  const int part = w & 1, half = w >> 1;
  const float* W = part ? Ws : Wf;
  float wreg[64];
#pragma unroll
  for (int k = 0; k < 64; ++k) wreg[k] = W[k * 64 + lane];
  const float bias = part ? bs[lane] : bf[lane];
  for (int n = blockIdx.x * 2 + half; n < N; n += gridDim.x * 2) {
    const float* xr = x + (size_t)n * 64;
    float acc = bias;
#pragma unroll
    for (int k = 0; k < 64; k += 4) {
      float4 xv = *(const float4*)(xr + k);
      acc = fmaf(xv.x, wreg[k], acc);
      acc = fmaf(xv.y, wreg[k + 1], acc);
      acc = fmaf(xv.z, wreg[k + 2], acc);
      acc = fmaf(xv.w, wreg[k + 3], acc);
    }
    Pdst[(size_t)n * 128 + part * 64 + lane] = acc;
  }
}

// ---------------- Prep (fused): cvt_x | bpack (K=96) | hist ----------------
// B row space kk=0..95: kk<32 -> W[128+kk] (eattr); kk>=32 -> W[32+kk] (x_src).
__global__ __launch_bounds__(256) void prep_kernel(
    const float* __restrict__ x, const float* __restrict__ Wf,
    const float* __restrict__ Ws, const int* __restrict__ ei,
    unsigned short* __restrict__ xbf, unsigned short* __restrict__ Bfrag,
    int* __restrict__ deg, int NCV, int total8, int E) {
  const int b = blockIdx.x, t = threadIdx.x;
  if (b < NCV) {
    int i = b * 256 + t;
    if (i < total8) {
      float4 a = ((const float4*)x)[i * 2];
      float4 c = ((const float4*)x)[i * 2 + 1];
      unsigned short o[8];
      o[0] = f2bf(a.x); o[1] = f2bf(a.y); o[2] = f2bf(a.z); o[3] = f2bf(a.w);
      o[4] = f2bf(c.x); o[5] = f2bf(c.y); o[6] = f2bf(c.z); o[7] = f2bf(c.w);
      ((uint4*)xbf)[i] = *(uint4*)o;
    }
  } else if (b < NCV + 6) {
    int g2 = (b - NCV) * 256 + t;
    if (g2 < 1536) {
      const int ks = g2 >> 9, t8 = (g2 >> 6) & 7, l = g2 & 63;
      const int q = l & 15, g = l >> 4;
      const float* W = (t8 < 4) ? Wf : Ws;
      const int col = (t8 & 3) * 16 + q;
      unsigned short out[8];
#pragma unroll
      for (int i = 0; i < 8; ++i) {
        int kk = ks * 32 + g * 8 + i;
        int wr = (kk < 32) ? (128 + kk) : (32 + kk);
        out[i] = f2bf(W[(size_t)wr * 64 + col]);
      }
      *(uint4*)&Bfrag[((size_t)(ks * 8 + t8) * 64 + l) * 8] = *(uint4*)out;
    }
  } else {
    int i = (b - NCV - 6) * 256 + t;
    if (i < E) atomicAdd(&deg[ei[E + i]], 1);
  }
}

// ---------------- CSR build: 3-phase parallel exclusive scan ----------------
__global__ __launch_bounds__(256) void scan_a(const int* __restrict__ deg,
                                              int* __restrict__ bsum, int N) {
  const int idx = blockIdx.x * 256 + threadIdx.x;
  int v = (idx < N) ? deg[idx] : 0;
#pragma unroll
  for (int o = 32; o > 0; o >>= 1) v += __shfl_down(v, o);
  __shared__ int ws4[4];
  if ((threadIdx.x & 63) == 0) ws4[threadIdx.x >> 6] = v;
  __syncthreads();
  if (threadIdx.x == 0) bsum[blockIdx.x] = ws4[0] + ws4[1] + ws4[2] + ws4[3];
}

__global__ __launch_bounds__(256) void scan_b(const int* __restrict__ bsum,
                                              int* __restrict__ bpre, int NB) {
  const int t = threadIdx.x;
  const int lane = t & 63, w = t >> 6;
  int v = (t < NB) ? bsum[t] : 0;
  int sc = v;
#pragma unroll
  for (int o = 1; o < 64; o <<= 1) {
    int u = __shfl_up(sc, o);
    if (lane >= o) sc += u;
  }
  __shared__ int wsum[4];
  if (lane == 63) wsum[w] = sc;
  __syncthreads();
  int add = 0;
#pragma unroll
  for (int k = 0; k < 4; ++k) add += (k < w) ? wsum[k] : 0;
  bpre[t] = (sc - v) + add;
}

__global__ __launch_bounds__(256) void scan_c(const int* __restrict__ deg,
                                              const int* __restrict__ bpre,
                                              int* __restrict__ cursor, int N) {
  const int t = threadIdx.x;
  const int lane = t & 63, w = t >> 6;
  const int idx = blockIdx.x * 256 + t;
  int d = (idx < N) ? deg[idx] : 0;
  int sc = d;
#pragma unroll
  for (int o = 1; o < 64; o <<= 1) {
    int u = __shfl_up(sc, o);
    if (lane >= o) sc += u;
  }
  __shared__ int wsum[4];
  if (lane == 63) wsum[w] = sc;
  __syncthreads();
  int add = bpre[blockIdx.x];
#pragma unroll
  for (int k = 0; k < 4; ++k) add += (k < w) ? wsum[k] : 0;
  if (idx < N) cursor[idx] = add + (sc - d);
}

// ---------------- CSR build: scatter (src,dst) + eattr->bf16 sorted ----------
__global__ __launch_bounds__(256) void scatter_pack(
    const int* __restrict__ ei, int* __restrict__ cursor,
    const float* __restrict__ eattr, int2* __restrict__ epair2,
    unsigned short* __restrict__ eabf, int E) {
  int i = blockIdx.x * 256 + threadIdx.x;
  if (i >= E) return;
  const int dst = ei[E + i];
  const int pos = atomicAdd(&cursor[dst], 1);
  epair2[pos] = make_int2(ei[i], dst);
  const float4* er = (const float4*)(eattr + (size_t)i * 32);
  unsigned short o[32];
#pragma unroll
  for (int k = 0; k < 8; ++k) {
    float4 v = er[k];
    o[k * 4] = f2bf(v.x); o[k * 4 + 1] = f2bf(v.y);
    o[k * 4 + 2] = f2bf(v.z); o[k * 4 + 3] = f2bf(v.w);
  }
  uint4* dp = (uint4*)(eabf + (size_t)pos * 32);
#pragma unroll
  for (int k = 0; k < 4; ++k) dp[k] = ((uint4*)o)[k];
}

// ---------------- K2: fused edge kernel (K=96, per-run Pdst lookup) ----------
// A(64x96 bf16) = [eattr | x_src] in 3 slabs [64][32bf16] (chunk-XOR swizzled,
// <=2-way banks). Staging = 3 global_load_lds per thread. One barrier/tile:
// MFMA -> scan+STAGE(t+1) (latency hides under epilogue) -> epilogue with
// per-run Pdst(f32) add + sigmoid*softplus + run-compressed atomics -> drain.
__global__ __launch_bounds__(256, 4) void edge_fused(
    const int2* __restrict__ epair2, const unsigned short* __restrict__ eabf,
    const unsigned short* __restrict__ xbf,
    const unsigned short* __restrict__ Bfrag, const float* __restrict__ Pdst,
    float* __restrict__ agg, int T, int N) {
  __shared__ __align__(16) unsigned char AshB[2][12288];
  __shared__ __align__(16) int metaLDS[2][64];

  const int tt = threadIdx.x, lane = tt & 63, w = tt >> 6;
  const int q = lane & 15, g = lane >> 4;

  // XCD-grouped contiguous tile range
  const int nB = gridDim.x;
  const int c = (blockIdx.x & 7) * (nB >> 3) + (blockIdx.x >> 3);
  const int q8 = T / nB, r8 = T - q8 * nB;
  const int t0 = c * q8 + min(c, r8);
  const int t1 = t0 + q8 + (c < r8 ? 1 : 0);
  if (t0 >= t1) return;

  bf16x8 Bf[3], Bs[3];
#pragma unroll
  for (int ks = 0; ks < 3; ++ks) {
    BU u1, u2;
    u1.u = ((const uint4*)Bfrag)[(ks * 8 + w) * 64 + lane];
    u2.u = ((const uint4*)Bfrag)[(ks * 8 + w + 4) * 64 + lane];
    Bf[ks] = u1.v; Bs[ks] = u2.v;
  }
  const int feat = w * 16 + q;

  auto SCAN = [&](int D, int slot) {
    if (w == 0) {
      int dp = __shfl_up(D, 1);
      int flag = (lane == 0 || D != dp) ? 1 : 0;
      int sc = flag;
#pragma unroll
      for (int o = 1; o < 64; o <<= 1) {
        int u = __shfl_up(sc, o);
        if (lane >= o) sc += u;
      }
      metaLDS[slot][lane] = ((sc - 1) << 20) | (D & 0xFFFFF);
    }
  };

  auto STAGE = [&](int tile, int bufSel, int Sreg) {
    const int row = (w << 4) + (lane >> 2);
    const int sw = (row ^ (row >> 2)) & 3;
    const int cc = (lane & 3) ^ sw;
    int sR = __shfl(Sreg, row);
    unsigned su = min((unsigned)sR, (unsigned)(N - 1));
    char* buf = (char*)&AshB[bufSel][0] + w * 1024;
    gload16(eabf + (size_t)tile * 2048 + row * 32 + cc * 8, buf);
    gload16(xbf + (size_t)su * 64 + cc * 8, buf + 4096);
    gload16(xbf + (size_t)su * 64 + 32 + cc * 8, buf + 8192);
  };

  // prologue
  {
    int2 p0 = epair2[(size_t)t0 * 64 + lane];
    SCAN(p0.y, 0);
    STAGE(t0, 0, p0.x);
  }
  int2 pn = make_int2(0, -1);
  if (t0 + 1 < t1) pn = epair2[(size_t)(t0 + 1) * 64 + lane];
  asm volatile("s_waitcnt vmcnt(0)" ::: "memory");
  __builtin_amdgcn_sched_barrier(0);
  __builtin_amdgcn_s_barrier();
  __builtin_amdgcn_sched_barrier(0);

  int pb = 0;
  for (int t = t0; t < t1; ++t) {
    // ---- MFMA over buf[pb] ----
    const char* bufc = (const char*)&AshB[0][0] + pb * 12288;
    f32x4 accf[4], accs[4];
#pragma unroll
    for (int mt = 0; mt < 4; ++mt) {
      accf[mt] = (f32x4){0.f, 0.f, 0.f, 0.f};
      accs[mt] = (f32x4){0.f, 0.f, 0.f, 0.f};
    }
#pragma unroll
    for (int ks = 0; ks < 3; ++ks) {
#pragma unroll
      for (int mt = 0; mt < 4; ++mt) {
        const int row = mt * 16 + q;
        const int sw = (row ^ (row >> 2)) & 3;
        const bf16x8 a =
            *(const bf16x8*)(bufc + ks * 4096 + row * 64 + ((g ^ sw) << 4));
        accf[mt] = __builtin_amdgcn_mfma_f32_16x16x32_bf16(a, Bf[ks],
                                                           accf[mt], 0, 0, 0);
        accs[mt] = __builtin_amdgcn_mfma_f32_16x16x32_bf16(a, Bs[ks],
                                                           accs[mt], 0, 0, 0);
      }
    }

    // ---- issue next tile's meta+stage early (hides under epilogue) ----
    if (t + 1 < t1) {
      SCAN(pn.y, pb ^ 1);
      STAGE(t + 1, pb ^ 1, pn.x);
      if (t + 2 < t1) pn = epair2[(size_t)(t + 2) * 64 + lane];
    }

    // ---- epilogue: per-run Pdst add, activations, run-compressed atomics ----
#pragma unroll
    for (int mt = 0; mt < 4; ++mt) {
      const int e0 = mt * 16 + g * 4;
      const uint4 mw = *(const uint4*)&metaLDS[pb][e0];
      unsigned cur = mw.x >> 20;
      unsigned d = mw.x & 0xFFFFFu;
      unsigned dl = min(d, (unsigned)(N - 1));
      float pf = Pdst[(size_t)dl * 128 + feat];
      float ps = Pdst[(size_t)dl * 128 + 64 + feat];
      float F = accf[mt][0] + pf;
      float Sv = accs[mt][0] + ps;
      float a_ = __builtin_amdgcn_rcpf(1.0f + __expf(-F)) *
                 (fmaxf(Sv, 0.f) + __logf(1.0f + __expf(-fabsf(Sv))));
#define STEP(UU, RIDX)                                                        \
  {                                                                           \
    unsigned rr = (UU) >> 20;                                                 \
    if (rr != cur) {                                                          \
      if (d < (unsigned)N) atomicAdd(&agg[(size_t)d * 64 + feat], a_);        \
      cur = rr; d = (UU) & 0xFFFFFu; dl = min(d, (unsigned)(N - 1));          \
      pf = Pdst[(size_t)dl * 128 + feat];                                     \
      ps = Pdst[(size_t)dl * 128 + 64 + feat];                                \
      a_ = 0.f;                                                               \
    }                                                                         \
    float F2 = accf[mt][RIDX] + pf;                                           \
    float S2 = accs[mt][RIDX] + ps;                                           \
    a_ += __builtin_amdgcn_rcpf(1.0f + __expf(-F2)) *                         \
          (fmaxf(S2, 0.f) + __logf(1.0f + __expf(-fabsf(S2))));               \
  }
      STEP(mw.y, 1)
      STEP(mw.z, 2)
      STEP(mw.w, 3)
#undef STEP
      if (d < (unsigned)N) atomicAdd(&agg[(size_t)d * 64 + feat], a_);
    }

    asm volatile("s_waitcnt vmcnt(0)" ::: "memory");
    __builtin_amdgcn_sched_barrier(0);
    __builtin_amdgcn_s_barrier();
    __builtin_amdgcn_sched_barrier(0);
    pb ^= 1;
  }
}

// ---------------- K3: per-feature reductions over agg and x ----------------
__global__ __launch_bounds__(256) void stats_kernel(
    const float* __restrict__ agg, const float* __restrict__ x,
    float* __restrict__ stats, int N) {
  const int f = threadIdx.x & 63;
  const int sub = threadIdx.x >> 6;
  float sa = 0, sa2 = 0, sx = 0, sx2 = 0, sax = 0;
  for (int r = blockIdx.x * 4 + sub; r < N; r += gridDim.x * 4) {
    float a = agg[(size_t)r * 64 + f];
    float xv = x[(size_t)r * 64 + f];
    sa += a; sa2 += a * a; sx += xv; sx2 += xv * xv; sax += a * xv;
  }
  __shared__ float lds[4][5][64];
  lds[sub][0][f] = sa; lds[sub][1][f] = sa2; lds[sub][2][f] = sx;
  lds[sub][3][f] = sx2; lds[sub][4][f] = sax;
  __syncthreads();
  if (sub == 0) {
#pragma unroll
    for (int i = 0; i < 5; ++i) {
      float v = lds[0][i][f] + lds[1][i][f] + lds[2][i][f] + lds[3][i][f];
      atomicAdd(&stats[i * 64 + f], v);
    }
  }
}

// ---------------- K5: finalize + BN+res+LN+softplus + pooling ----------------
__global__ __launch_bounds__(256) void node_finish(
    const float* __restrict__ stats, const float* __restrict__ bn_w,
    const float* __restrict__ bn_b, const float* __restrict__ agg,
    const float* __restrict__ x, const int* __restrict__ batch,
    const float* __restrict__ ln_w, const float* __restrict__ ln_b,
    float* __restrict__ add_pool, float* __restrict__ counts, int N,
    int chunk) {
  const int f = threadIdx.x & 63;
  const int sub = threadIdx.x >> 6;
  const float Nf = (float)N;
  const float invN = 1.0f / Nf;
  float Sa = stats[f], Sa2 = stats[64 + f], Sx = stats[128 + f],
        Sx2 = stats[192 + f], Sax = stats[256 + f];
  float mu = Sa * invN;
  float var = Sa2 * invN - mu * mu;
  const float alpha = bn_w[f] / sqrtf(var + EPSF);
  const float beta = bn_b[f] - mu * alpha;
  float Sh = alpha * Sa + Nf * beta + Sx;
  float Sh2 = alpha * alpha * Sa2 + Sx2 + Nf * beta * beta +
              2.f * alpha * Sax + 2.f * alpha * beta * Sa + 2.f * beta * Sx;
#pragma unroll
  for (int o = 32; o > 0; o >>= 1) {
    Sh += __shfl_xor(Sh, o);
    Sh2 += __shfl_xor(Sh2, o);
  }
  const float cnt = Nf * 64.0f;
  const float mean = Sh / cnt;
  const float msq = Sh2 / cnt - mean * mean;
  const float rden = 1.0f / (sqrtf(fmaxf(msq, 0.f)) + EPSF);
  const float lw = ln_w[f] * rden;
  const float lb = ln_b[f];

  const int r0 = blockIdx.x * chunk;
  const int r1 = min(N, r0 + chunk);
  float acc = 0.f, cacc = 0.f;
  int curg = -1;
  for (int r = r0 + sub; r < r1; r += 4) {
    int g = batch[r];
    if (g != curg) {
      if (curg >= 0) {
        atomicAdd(&add_pool[(size_t)curg * 64 + f], acc);
        if (f == 0) atomicAdd(&counts[curg], cacc);
      }
      curg = g; acc = 0.f; cacc = 0.f;
    }
    float h = fmaf(alpha, agg[(size_t)r * 64 + f], beta) + x[(size_t)r * 64 + f];
    float v = (h - mean) * lw + lb;
    float sp = fmaxf(v, 0.f) + __logf(1.0f + __expf(-fabsf(v)));
    acc += sp; cacc += 1.f;
  }
  if (curg >= 0) {
    atomicAdd(&add_pool[(size_t)curg * 64 + f], acc);
    if (f == 0) atomicAdd(&counts[curg], cacc);
  }
}

// ---------------- K6: graph head (vectorized) ----------------
__global__ __launch_bounds__(1024) void graph_out(
    const float* __restrict__ add_pool, const float* __restrict__ counts,
    const float* __restrict__ Wl, const float* __restrict__ bl,
    const float* __restrict__ w4, const float* __restrict__ b4,
    float* __restrict__ out, int G) {
  const int t = threadIdx.x;
  const int g = t >> 1, c = t & 1;
  float cnt = fmaxf(counts[g], 1.0f);
  float inv = 1.0f / cnt;
  const float4* ap4 = (const float4*)(add_pool + (size_t)g * 64);
  const float4* W4 = (const float4*)Wl;
  float v = bl[c];
#pragma unroll 4
  for (int k4 = 0; k4 < 16; ++k4) {
    float4 a4 = ap4[k4];
    float4 wa = W4[k4 * 2];
    float4 wb = W4[k4 * 2 + 1];
    float4 wc = W4[32 + k4 * 2];
    float4 wd = W4[32 + k4 * 2 + 1];
    float m0 = c ? wa.y : wa.x, m1 = c ? wa.w : wa.z;
    float m2 = c ? wb.y : wb.x, m3 = c ? wb.w : wb.z;
    float a0 = c ? wc.y : wc.x, a1 = c ? wc.w : wc.z;
    float a2 = c ? wd.y : wd.x, a3 = c ? wd.w : wd.z;
    v = fmaf(a4.x, fmaf(m0, inv, a0), v);
    v = fmaf(a4.y, fmaf(m1, inv, a1), v);
    v = fmaf(a4.z, fmaf(m2, inv, a2), v);
    v = fmaf(a4.w, fmaf(m3, inv, a3), v);
  }

  __shared__ float red[16];
  __shared__ float bc[2];
  float sum = v;
#pragma unroll
  for (int o = 32; o > 0; o >>= 1) sum += __shfl_down(sum, o);
  if ((t & 63) == 0) red[t >> 6] = sum;
  __syncthreads();
  if (t == 0) {
    float tot = 0;
#pragma unroll
    for (int i = 0; i < 16; ++i) tot += red[i];
    bc[0] = tot * (1.0f / 1024.0f);
  }
  __syncthreads();
  const float mean = bc[0];
  const float xc = v - mean;
  float sq = xc * xc;
  __syncthreads();
#pragma unroll
  for (int o = 32; o > 0; o >>= 1) sq += __shfl_down(sq, o);
  if ((t & 63) == 0) red[t >> 6] = sq;
  __syncthreads();
  if (t == 0) {
    float tot = 0;
#pragma unroll
    for (int i = 0; i < 16; ++i) tot += red[i];
    bc[1] = 1.0f / (sqrtf(tot * (1.0f / 1024.0f)) + EPSF);
  }
  __syncthreads();
  out[t] = xc * bc[1] * w4[c] + b4[c];
}

extern "C" void kernel_launch(void* const* d_in, const int* in_sizes, int n_in,
                              void* d_out, int out_size, void* d_ws,
                              size_t ws_size, hipStream_t stream) {
  const float* x = (const float*)d_in[0];
  const int* ei = (const int*)d_in[1];
  const float* eattr = (const float*)d_in[2];
  const int* batch = (const int*)d_in[3];
  const float* Wf = (const float*)d_in[4];
  const float* bf = (const float*)d_in[5];
  const float* Ws = (const float*)d_in[6];
  const float* bs = (const float*)d_in[7];
  const float* bn_w = (const float*)d_in[8];
  const float* bn_b = (const float*)d_in[9];
  const float* ln_w = (const float*)d_in[10];
  const float* ln_b = (const float*)d_in[11];
  const float* Wl = (const float*)d_in[12];
  const float* bl = (const float*)d_in[13];
  const float* w4 = (const float*)d_in[14];
  const float* b4 = (const float*)d_in[15];

  const int N = in_sizes[0] / 64;
  const int E = in_sizes[2] / 32;
  const int G = 512;
  const int NB = (N + 255) / 256;
  const int T = (E + 63) / 64;
  const int NCV = (N * 8 + 255) / 256;
  const int NH = (E + 255) / 256;

  // Workspace layout (floats; each chunk multiple of 4 => 16B alignment).
  float* ws = (float*)d_ws;
  float* agg = ws;                                   // N*64  [zeroed]
  float* stats = agg + (size_t)N * 64;               // 320   [zeroed]
  float* add_pool = stats + 320;                     // G*64  [zeroed]
  float* counts = add_pool + (size_t)G * 64;         // G     [zeroed]
  int* deg = (int*)(counts + G);                     // N     [zeroed]
  int* cursor = deg + N;                             // N
  int* bsum = cursor + N;                            // 256
  int* bpre = bsum + 256;                            // 256
  unsigned short* Bfrag = (unsigned short*)(bpre + 256);   // 12288 ush
  unsigned short* xbf = Bfrag + 12288;                     // N*64 ush
  float* Pdst = (float*)(xbf + (size_t)N * 64);            // N*128 f
  unsigned short* eabf = (unsigned short*)(Pdst + (size_t)N * 128);  // T*2048
  int2* epair2 = (int2*)(eabf + (size_t)T * 2048);         // T*64 int2

  size_t zeroFloats = (size_t)N * 64 + 320 + (size_t)G * 64 + G + N;
  hipMemsetAsync(agg, 0, zeroFloats * sizeof(float), stream);
  const int padE = T * 64 - E;
  if (padE > 0) hipMemsetAsync(epair2 + E, 0xFF, (size_t)padE * 8, stream);

  prep_kernel<<<NCV + 6 + NH, 256, 0, stream>>>(x, Wf, Ws, ei, xbf, Bfrag, deg,
                                                NCV, N * 8, E);
  node_gemm<<<2048, 256, 0, stream>>>(x, Wf, bf, Ws, bs, Pdst, N);
  scan_a<<<NB, 256, 0, stream>>>(deg, bsum, N);
  scan_b<<<1, 256, 0, stream>>>(bsum, bpre, NB);
  scan_c<<<NB, 256, 0, stream>>>(deg, bpre, cursor, N);
  scatter_pack<<<NH, 256, 0, stream>>>(ei, cursor, eattr, epair2, eabf, E);
  edge_fused<<<1280, 256, 0, stream>>>(epair2, eabf, xbf, Bfrag, Pdst, agg, T,
                                       N);
  stats_kernel<<<512, 256, 0, stream>>>(agg, x, stats, N);
  const int chunk = (N + 511) / 512;
  node_finish<<<512, 256, 0, stream>>>(stats, bn_w, bn_b, agg, x, batch, ln_w,
                                       ln_b, add_pool, counts, N, chunk);
  graph_out<<<1, 1024, 0, stream>>>(add_pool, counts, Wl, bl, w4, b4,
                                    (float*)d_out, G);
}

// Round 11
// 380.835 us; speedup vs baseline: 1.0321x; 1.0321x over previous
//
#include <hip/hip_runtime.h>
#include <math.h>

#define EPSF 1e-5f

typedef short bf16x8 __attribute__((ext_vector_type(8)));
typedef float f32x4 __attribute__((ext_vector_type(4)));

static __device__ __forceinline__ unsigned short f2bf(float x) {
  unsigned u = __float_as_uint(x);
  unsigned r = (u + 0x7FFFu + ((u >> 16) & 1u)) >> 16;
  return (unsigned short)r;
}

static __device__ __forceinline__ float msgv(float F, float S) {
  float sig = __builtin_amdgcn_rcpf(1.0f + __expf(-F));
  float sp = fmaxf(S, 0.f) + __logf(1.0f + __expf(-fabsf(S)));
  return sig * sp;
}

// ---------------- Prep (fused): cvt_x | bpack_edge(K=96) | bpack_node | hist --
// Edge B rows kk=0..95: kk<32 -> W[128+kk] (eattr); kk>=32 -> W[32+kk] (x_src).
// Node B rows kk=0..63 -> W[kk] (x_dst). Frag: lane l holds
// B[k=(l>>4)*8+i][col=(t8&3)*16+(l&15)], t8<4 => Wf else Ws.
__global__ __launch_bounds__(256) void prep_kernel(
    const float* __restrict__ x, const float* __restrict__ Wf,
    const float* __restrict__ Ws, const int* __restrict__ ei,
    unsigned short* __restrict__ xbf, unsigned short* __restrict__ Bfrag,
    unsigned short* __restrict__ Bfrag2, int* __restrict__ deg, int NCV,
    int total8, int E) {
  const int b = blockIdx.x, t = threadIdx.x;
  if (b < NCV) {
    int i = b * 256 + t;
    if (i < total8) {
      float4 a = ((const float4*)x)[i * 2];
      float4 c = ((const float4*)x)[i * 2 + 1];
      unsigned short o[8];
      o[0] = f2bf(a.x); o[1] = f2bf(a.y); o[2] = f2bf(a.z); o[3] = f2bf(a.w);
      o[4] = f2bf(c.x); o[5] = f2bf(c.y); o[6] = f2bf(c.z); o[7] = f2bf(c.w);
      ((uint4*)xbf)[i] = *(uint4*)o;
    }
  } else if (b < NCV + 6) {
    int g2 = (b - NCV) * 256 + t;
    if (g2 < 1536) {
      const int ks = g2 >> 9, t8 = (g2 >> 6) & 7, l = g2 & 63;
      const int q = l & 15, g = l >> 4;
      const float* W = (t8 < 4) ? Wf : Ws;
      const int col = (t8 & 3) * 16 + q;
      unsigned short out[8];
#pragma unroll
      for (int i = 0; i < 8; ++i) {
        int kk = ks * 32 + g * 8 + i;
        int wr = (kk < 32) ? (128 + kk) : (32 + kk);
        out[i] = f2bf(W[(size_t)wr * 64 + col]);
      }
      *(uint4*)&Bfrag[((size_t)(ks * 8 + t8) * 64 + l) * 8] = *(uint4*)out;
    }
  } else if (b < NCV + 10) {
    int g2 = (b - NCV - 6) * 256 + t;
    if (g2 < 1024) {
      const int ks = g2 >> 9, t8 = (g2 >> 6) & 7, l = g2 & 63;
      const int q = l & 15, g = l >> 4;
      const float* W = (t8 < 4) ? Wf : Ws;
      const int col = (t8 & 3) * 16 + q;
      unsigned short out[8];
#pragma unroll
      for (int i = 0; i < 8; ++i) {
        int kk = ks * 32 + g * 8 + i;
        out[i] = f2bf(W[(size_t)kk * 64 + col]);
      }
      *(uint4*)&Bfrag2[((size_t)(ks * 8 + t8) * 64 + l) * 8] = *(uint4*)out;
    }
  } else {
    int i = (b - NCV - 10) * 256 + t;
    if (i < E) atomicAdd(&deg[ei[E + i]], 1);
  }
}

// ---------------- K1: Pdst = xbf @ Wd(64x128) + bias, MFMA ----------------
__global__ __launch_bounds__(256, 4) void node_mfma(
    const unsigned short* __restrict__ xbf,
    const unsigned short* __restrict__ Bfrag2, const float* __restrict__ bf_,
    const float* __restrict__ bs_, float* __restrict__ Pdst, int N) {
  __shared__ __align__(16) short Bsh[16][64][8];  // 16 KB
  for (int i = threadIdx.x; i < 1024; i += 256)
    ((uint4*)Bsh)[i] = ((const uint4*)Bfrag2)[i];
  __syncthreads();
  const int lane = threadIdx.x & 63, w = threadIdx.x >> 6;
  const int q = lane & 15, g = lane >> 4;
  const int row0 = blockIdx.x * 64;
  const float bfv = bf_[w * 16 + q], bsv = bs_[w * 16 + q];
  f32x4 accf[4], accs[4];
#pragma unroll
  for (int mt = 0; mt < 4; ++mt) {
    accf[mt] = (f32x4){0.f, 0.f, 0.f, 0.f};
    accs[mt] = (f32x4){0.f, 0.f, 0.f, 0.f};
  }
#pragma unroll
  for (int ks = 0; ks < 2; ++ks) {
    const bf16x8 Bfr = *(const bf16x8*)&Bsh[ks * 8 + w][lane][0];
    const bf16x8 Bsr = *(const bf16x8*)&Bsh[ks * 8 + 4 + w][lane][0];
#pragma unroll
    for (int mt = 0; mt < 4; ++mt) {
      int row = min(row0 + mt * 16 + q, N - 1);
      const bf16x8 a = *(const bf16x8*)(xbf + (size_t)row * 64 + ks * 32 + g * 8);
      accf[mt] = __builtin_amdgcn_mfma_f32_16x16x32_bf16(a, Bfr, accf[mt], 0, 0, 0);
      accs[mt] = __builtin_amdgcn_mfma_f32_16x16x32_bf16(a, Bsr, accs[mt], 0, 0, 0);
    }
  }
#pragma unroll
  for (int mt = 0; mt < 4; ++mt) {
#pragma unroll
    for (int r = 0; r < 4; ++r) {
      int row = row0 + mt * 16 + g * 4 + r;
      if (row < N) {
        Pdst[(size_t)row * 128 + w * 16 + q] = accf[mt][r] + bfv;
        Pdst[(size_t)row * 128 + 64 + w * 16 + q] = accs[mt][r] + bsv;
      }
    }
  }
}

// ---------------- CSR build: 3-phase parallel exclusive scan ----------------
__global__ __launch_bounds__(256) void scan_a(const int* __restrict__ deg,
                                              int* __restrict__ bsum, int N) {
  const int idx = blockIdx.x * 256 + threadIdx.x;
  int v = (idx < N) ? deg[idx] : 0;
#pragma unroll
  for (int o = 32; o > 0; o >>= 1) v += __shfl_down(v, o);
  __shared__ int ws4[4];
  if ((threadIdx.x & 63) == 0) ws4[threadIdx.x >> 6] = v;
  __syncthreads();
  if (threadIdx.x == 0) bsum[blockIdx.x] = ws4[0] + ws4[1] + ws4[2] + ws4[3];
}

__global__ __launch_bounds__(256) void scan_b(const int* __restrict__ bsum,
                                              int* __restrict__ bpre, int NB) {
  const int t = threadIdx.x;
  const int lane = t & 63, w = t >> 6;
  int v = (t < NB) ? bsum[t] : 0;
  int sc = v;
#pragma unroll
  for (int o = 1; o < 64; o <<= 1) {
    int u = __shfl_up(sc, o);
    if (lane >= o) sc += u;
  }
  __shared__ int wsum[4];
  if (lane == 63) wsum[w] = sc;
  __syncthreads();
  int add = 0;
#pragma unroll
  for (int k = 0; k < 4; ++k) add += (k < w) ? wsum[k] : 0;
  bpre[t] = (sc - v) + add;
}

__global__ __launch_bounds__(256) void scan_c(const int* __restrict__ deg,
                                              const int* __restrict__ bpre,
                                              int* __restrict__ cursor, int N) {
  const int t = threadIdx.x;
  const int lane = t & 63, w = t >> 6;
  const int idx = blockIdx.x * 256 + t;
  int d = (idx < N) ? deg[idx] : 0;
  int sc = d;
#pragma unroll
  for (int o = 1; o < 64; o <<= 1) {
    int u = __shfl_up(sc, o);
    if (lane >= o) sc += u;
  }
  __shared__ int wsum[4];
  if (lane == 63) wsum[w] = sc;
  __syncthreads();
  int add = bpre[blockIdx.x];
#pragma unroll
  for (int k = 0; k < 4; ++k) add += (k < w) ? wsum[k] : 0;
  if (idx < N) cursor[idx] = add + (sc - d);
}

// ---------------- CSR build: scatter (src,dst) + eattr->bf16 sorted ----------
__global__ __launch_bounds__(256) void scatter_pack(
    const int* __restrict__ ei, int* __restrict__ cursor,
    const float* __restrict__ eattr, int2* __restrict__ epair2,
    unsigned short* __restrict__ eabf, int E) {
  int i = blockIdx.x * 256 + threadIdx.x;
  if (i >= E) return;
  const int dst = ei[E + i];
  const int pos = atomicAdd(&cursor[dst], 1);
  epair2[pos] = make_int2(ei[i], dst);
  const float4* er = (const float4*)(eattr + (size_t)i * 32);
  unsigned short o[32];
#pragma unroll
  for (int k = 0; k < 8; ++k) {
    float4 v = er[k];
    o[k * 4] = f2bf(v.x); o[k * 4 + 1] = f2bf(v.y);
    o[k * 4 + 2] = f2bf(v.z); o[k * 4 + 3] = f2bf(v.w);
  }
  uint4* dp = (uint4*)(eabf + (size_t)pos * 32);
#pragma unroll
  for (int k = 0; k < 4; ++k) dp[k] = ((uint4*)o)[k];
}

// ---------------- K2: barrier-free edge kernel, one WAVE per 16-edge tile ----
// A(16x96 bf16) = [eattr | x_src] loaded global->registers (3 dwordx4/lane).
// B(96x128) in LDS (written once). Per-lane epilogue: 4 edges x 4 feat-cols,
// per-run Pdst add + sigmoid*softplus + run-compressed atomics into agg.
// Next tile's epair+A prefetched in registers. No barriers in the loop.
__global__ __launch_bounds__(256, 4) void edge_fused(
    const int2* __restrict__ epair2, const unsigned short* __restrict__ eabf,
    const unsigned short* __restrict__ xbf,
    const unsigned short* __restrict__ Bfrag, const float* __restrict__ Pdst,
    float* __restrict__ agg, int T16, int N) {
  __shared__ __align__(16) short Bsh[24][64][8];  // 24 KB
  for (int i = threadIdx.x; i < 1536; i += 256)
    ((uint4*)Bsh)[i] = ((const uint4*)Bfrag)[i];
  __syncthreads();

  const int lane = threadIdx.x & 63, w = threadIdx.x >> 6;
  const int q = lane & 15, g = lane >> 4;

  // XCD-grouped contiguous tile range per block; waves stride by 4 within it.
  const int nB = gridDim.x;
  const int cb = (blockIdx.x & 7) * (nB >> 3) + (blockIdx.x >> 3);
  const int q8 = T16 / nB, r8 = T16 - q8 * nB;
  const int t0 = cb * q8 + min(cb, r8);
  const int t1 = t0 + q8 + (cb < r8 ? 1 : 0);

  int t = t0 + w;
  if (t >= t1) return;

  int2 p = epair2[(size_t)t * 16 + q];
  bf16x8 aE = *(const bf16x8*)(eabf + (size_t)t * 512 + q * 32 + g * 8);
  unsigned su = min((unsigned)p.x, (unsigned)(N - 1));
  bf16x8 aX0 = *(const bf16x8*)(xbf + (size_t)su * 64 + g * 8);
  bf16x8 aX1 = *(const bf16x8*)(xbf + (size_t)su * 64 + 32 + g * 8);

  while (true) {
    const int tn = t + 4;
    const bool more = (tn < t1);
    int2 pn = p;
    bf16x8 aEn = aE, aX0n = aX0, aX1n = aX1;
    if (more) {  // prefetch next tile (hides under MFMA + epilogue)
      pn = epair2[(size_t)tn * 16 + q];
      aEn = *(const bf16x8*)(eabf + (size_t)tn * 512 + q * 32 + g * 8);
      unsigned sn = min((unsigned)pn.x, (unsigned)(N - 1));
      aX0n = *(const bf16x8*)(xbf + (size_t)sn * 64 + g * 8);
      aX1n = *(const bf16x8*)(xbf + (size_t)sn * 64 + 32 + g * 8);
    }

    // ---- 24 MFMA: 8 col-tiles (4 f + 4 s) x 3 K-slabs ----
    f32x4 accf[4], accs[4];
#pragma unroll
    for (int nt = 0; nt < 4; ++nt) {
      f32x4 z = {0.f, 0.f, 0.f, 0.f};
      accf[nt] = __builtin_amdgcn_mfma_f32_16x16x32_bf16(
          aE, *(const bf16x8*)&Bsh[nt][lane][0], z, 0, 0, 0);
      accf[nt] = __builtin_amdgcn_mfma_f32_16x16x32_bf16(
          aX0, *(const bf16x8*)&Bsh[8 + nt][lane][0], accf[nt], 0, 0, 0);
      accf[nt] = __builtin_amdgcn_mfma_f32_16x16x32_bf16(
          aX1, *(const bf16x8*)&Bsh[16 + nt][lane][0], accf[nt], 0, 0, 0);
      f32x4 z2 = {0.f, 0.f, 0.f, 0.f};
      accs[nt] = __builtin_amdgcn_mfma_f32_16x16x32_bf16(
          aE, *(const bf16x8*)&Bsh[4 + nt][lane][0], z2, 0, 0, 0);
      accs[nt] = __builtin_amdgcn_mfma_f32_16x16x32_bf16(
          aX0, *(const bf16x8*)&Bsh[12 + nt][lane][0], accs[nt], 0, 0, 0);
      accs[nt] = __builtin_amdgcn_mfma_f32_16x16x32_bf16(
          aX1, *(const bf16x8*)&Bsh[20 + nt][lane][0], accs[nt], 0, 0, 0);
    }

    // ---- epilogue: lane owns edges g*4+r, feat cols cg*16+q ----
    int d0 = __shfl(p.y, g * 4);
    int d1 = __shfl(p.y, g * 4 + 1);
    int d2 = __shfl(p.y, g * 4 + 2);
    int d3 = __shfl(p.y, g * 4 + 3);
#pragma unroll
    for (int cg = 0; cg < 4; ++cg) {
      const int feat = cg * 16 + q;
      const float* Pf = Pdst + feat;
      unsigned dc = (unsigned)d0;
      unsigned dl = min(dc, (unsigned)(N - 1));
      float pf = Pf[(size_t)dl * 128];
      float ps = Pf[(size_t)dl * 128 + 64];
      float a_ = msgv(accf[cg][0] + pf, accs[cg][0] + ps);
#define STEP(DR, RIDX)                                                        \
  {                                                                           \
    unsigned dr = (unsigned)(DR);                                             \
    if (dr != dc) {                                                           \
      if (dc < (unsigned)N) atomicAdd(&agg[(size_t)dc * 64 + feat], a_);      \
      dc = dr; dl = min(dc, (unsigned)(N - 1));                               \
      pf = Pf[(size_t)dl * 128];                                              \
      ps = Pf[(size_t)dl * 128 + 64];                                         \
      a_ = 0.f;                                                               \
    }                                                                         \
    a_ += msgv(accf[cg][RIDX] + pf, accs[cg][RIDX] + ps);                     \
  }
      STEP(d1, 1)
      STEP(d2, 2)
      STEP(d3, 3)
#undef STEP
      if (dc < (unsigned)N) atomicAdd(&agg[(size_t)dc * 64 + feat], a_);
    }

    if (!more) break;
    p = pn; aE = aEn; aX0 = aX0n; aX1 = aX1n; t = tn;
  }
}

// ---------------- K3: per-feature reductions over agg and x ----------------
__global__ __launch_bounds__(256) void stats_kernel(
    const float* __restrict__ agg, const float* __restrict__ x,
    float* __restrict__ stats, int N) {
  const int f = threadIdx.x & 63;
  const int sub = threadIdx.x >> 6;
  float sa = 0, sa2 = 0, sx = 0, sx2 = 0, sax = 0;
  for (int r = blockIdx.x * 4 + sub; r < N; r += gridDim.x * 4) {
    float a = agg[(size_t)r * 64 + f];
    float xv = x[(size_t)r * 64 + f];
    sa += a; sa2 += a * a; sx += xv; sx2 += xv * xv; sax += a * xv;
  }
  __shared__ float lds[4][5][64];
  lds[sub][0][f] = sa; lds[sub][1][f] = sa2; lds[sub][2][f] = sx;
  lds[sub][3][f] = sx2; lds[sub][4][f] = sax;
  __syncthreads();
  if (sub == 0) {
#pragma unroll
    for (int i = 0; i < 5; ++i) {
      float v = lds[0][i][f] + lds[1][i][f] + lds[2][i][f] + lds[3][i][f];
      atomicAdd(&stats[i * 64 + f], v);
    }
  }
}

// ---------------- K5: finalize + BN+res+LN+softplus + pooling ----------------
__global__ __launch_bounds__(256) void node_finish(
    const float* __restrict__ stats, const float* __restrict__ bn_w,
    const float* __restrict__ bn_b, const float* __restrict__ agg,
    const float* __restrict__ x, const int* __restrict__ batch,
    const float* __restrict__ ln_w, const float* __restrict__ ln_b,
    float* __restrict__ add_pool, float* __restrict__ counts, int N,
    int chunk) {
  const int f = threadIdx.x & 63;
  const int sub = threadIdx.x >> 6;
  const float Nf = (float)N;
  const float invN = 1.0f / Nf;
  float Sa = stats[f], Sa2 = stats[64 + f], Sx = stats[128 + f],
        Sx2 = stats[192 + f], Sax = stats[256 + f];
  float mu = Sa * invN;
  float var = Sa2 * invN - mu * mu;
  const float alpha = bn_w[f] / sqrtf(var + EPSF);
  const float beta = bn_b[f] - mu * alpha;
  float Sh = alpha * Sa + Nf * beta + Sx;
  float Sh2 = alpha * alpha * Sa2 + Sx2 + Nf * beta * beta +
              2.f * alpha * Sax + 2.f * alpha * beta * Sa + 2.f * beta * Sx;
#pragma unroll
  for (int o = 32; o > 0; o >>= 1) {
    Sh += __shfl_xor(Sh, o);
    Sh2 += __shfl_xor(Sh2, o);
  }
  const float cnt = Nf * 64.0f;
  const float mean = Sh / cnt;
  const float msq = Sh2 / cnt - mean * mean;
  const float rden = 1.0f / (sqrtf(fmaxf(msq, 0.f)) + EPSF);
  const float lw = ln_w[f] * rden;
  const float lb = ln_b[f];

  const int r0 = blockIdx.x * chunk;
  const int r1 = min(N, r0 + chunk);
  float acc = 0.f, cacc = 0.f;
  int curg = -1;
  for (int r = r0 + sub; r < r1; r += 4) {
    int g = batch[r];
    if (g != curg) {
      if (curg >= 0) {
        atomicAdd(&add_pool[(size_t)curg * 64 + f], acc);
        if (f == 0) atomicAdd(&counts[curg], cacc);
      }
      curg = g; acc = 0.f; cacc = 0.f;
    }
    float h = fmaf(alpha, agg[(size_t)r * 64 + f], beta) + x[(size_t)r * 64 + f];
    float v = (h - mean) * lw + lb;
    float sp = fmaxf(v, 0.f) + __logf(1.0f + __expf(-fabsf(v)));
    acc += sp; cacc += 1.f;
  }
  if (curg >= 0) {
    atomicAdd(&add_pool[(size_t)curg * 64 + f], acc);
    if (f == 0) atomicAdd(&counts[curg], cacc);
  }
}

// ---------------- K6: graph head (vectorized) ----------------
__global__ __launch_bounds__(1024) void graph_out(
    const float* __restrict__ add_pool, const float* __restrict__ counts,
    const float* __restrict__ Wl, const float* __restrict__ bl,
    const float* __restrict__ w4, const float* __restrict__ b4,
    float* __restrict__ out, int G) {
  const int t = threadIdx.x;
  const int g = t >> 1, c = t & 1;
  float cnt = fmaxf(counts[g], 1.0f);
  float inv = 1.0f / cnt;
  const float4* ap4 = (const float4*)(add_pool + (size_t)g * 64);
  const float4* W4 = (const float4*)Wl;
  float v = bl[c];
#pragma unroll 4
  for (int k4 = 0; k4 < 16; ++k4) {
    float4 a4 = ap4[k4];
    float4 wa = W4[k4 * 2];
    float4 wb = W4[k4 * 2 + 1];
    float4 wc = W4[32 + k4 * 2];
    float4 wd = W4[32 + k4 * 2 + 1];
    float m0 = c ? wa.y : wa.x, m1 = c ? wa.w : wa.z;
    float m2 = c ? wb.y : wb.x, m3 = c ? wb.w : wb.z;
    float a0 = c ? wc.y : wc.x, a1 = c ? wc.w : wc.z;
    float a2 = c ? wd.y : wd.x, a3 = c ? wd.w : wd.z;
    v = fmaf(a4.x, fmaf(m0, inv, a0), v);
    v = fmaf(a4.y, fmaf(m1, inv, a1), v);
    v = fmaf(a4.z, fmaf(m2, inv, a2), v);
    v = fmaf(a4.w, fmaf(m3, inv, a3), v);
  }

  __shared__ float red[16];
  __shared__ float bc[2];
  float sum = v;
#pragma unroll
  for (int o = 32; o > 0; o >>= 1) sum += __shfl_down(sum, o);
  if ((t & 63) == 0) red[t >> 6] = sum;
  __syncthreads();
  if (t == 0) {
    float tot = 0;
#pragma unroll
    for (int i = 0; i < 16; ++i) tot += red[i];
    bc[0] = tot * (1.0f / 1024.0f);
  }
  __syncthreads();
  const float mean = bc[0];
  const float xc = v - mean;
  float sq = xc * xc;
  __syncthreads();
#pragma unroll
  for (int o = 32; o > 0; o >>= 1) sq += __shfl_down(sq, o);
  if ((t & 63) == 0) red[t >> 6] = sq;
  __syncthreads();
  if (t == 0) {
    float tot = 0;
#pragma unroll
    for (int i = 0; i < 16; ++i) tot += red[i];
    bc[1] = 1.0f / (sqrtf(tot * (1.0f / 1024.0f)) + EPSF);
  }
  __syncthreads();
  out[t] = xc * bc[1] * w4[c] + b4[c];
}

extern "C" void kernel_launch(void* const* d_in, const int* in_sizes, int n_in,
                              void* d_out, int out_size, void* d_ws,
                              size_t ws_size, hipStream_t stream) {
  const float* x = (const float*)d_in[0];
  const int* ei = (const int*)d_in[1];
  const float* eattr = (const float*)d_in[2];
  const int* batch = (const int*)d_in[3];
  const float* Wf = (const float*)d_in[4];
  const float* bf = (const float*)d_in[5];
  const float* Ws = (const float*)d_in[6];
  const float* bs = (const float*)d_in[7];
  const float* bn_w = (const float*)d_in[8];
  const float* bn_b = (const float*)d_in[9];
  const float* ln_w = (const float*)d_in[10];
  const float* ln_b = (const float*)d_in[11];
  const float* Wl = (const float*)d_in[12];
  const float* bl = (const float*)d_in[13];
  const float* w4 = (const float*)d_in[14];
  const float* b4 = (const float*)d_in[15];

  const int N = in_sizes[0] / 64;
  const int E = in_sizes[2] / 32;
  const int G = 512;
  const int NB = (N + 255) / 256;
  const int T16 = (E + 15) / 16;
  const int NCV = (N * 8 + 255) / 256;
  const int NH = (E + 255) / 256;

  // Workspace layout (floats; each chunk multiple of 4 => 16B alignment).
  float* ws = (float*)d_ws;
  float* agg = ws;                                   // N*64  [zeroed]
  float* stats = agg + (size_t)N * 64;               // 320   [zeroed]
  float* add_pool = stats + 320;                     // G*64  [zeroed]
  float* counts = add_pool + (size_t)G * 64;         // G     [zeroed]
  int* deg = (int*)(counts + G);                     // N     [zeroed]
  int* cursor = deg + N;                             // N
  int* bsum = cursor + N;                            // 256
  int* bpre = bsum + 256;                            // 256
  unsigned short* Bfrag = (unsigned short*)(bpre + 256);   // 12288 ush (24KB)
  unsigned short* Bfrag2 = Bfrag + 12288;                  // 8192 ush (16KB)
  unsigned short* xbf = Bfrag2 + 8192;                     // N*64 ush
  float* Pdst = (float*)(xbf + (size_t)N * 64);            // N*128 f
  unsigned short* eabf = (unsigned short*)(Pdst + (size_t)N * 128);  // T16*512
  int2* epair2 = (int2*)(eabf + (size_t)T16 * 512);        // T16*16 int2

  size_t zeroFloats = (size_t)N * 64 + 320 + (size_t)G * 64 + G + N;
  hipMemsetAsync(agg, 0, zeroFloats * sizeof(float), stream);
  const int padE = T16 * 16 - E;
  if (padE > 0) hipMemsetAsync(epair2 + E, 0xFF, (size_t)padE * 8, stream);

  prep_kernel<<<NCV + 10 + NH, 256, 0, stream>>>(x, Wf, Ws, ei, xbf, Bfrag,
                                                 Bfrag2, deg, NCV, N * 8, E);
  node_mfma<<<(N + 63) / 64, 256, 0, stream>>>(xbf, Bfrag2, bf, bs, Pdst, N);
  scan_a<<<NB, 256, 0, stream>>>(deg, bsum, N);
  scan_b<<<1, 256, 0, stream>>>(bsum, bpre, NB);
  scan_c<<<NB, 256, 0, stream>>>(deg, bpre, cursor, N);
  scatter_pack<<<NH, 256, 0, stream>>>(ei, cursor, eattr, epair2, eabf, E);
  edge_fused<<<1024, 256, 0, stream>>>(epair2, eabf, xbf, Bfrag, Pdst, agg,
                                       T16, N);
  stats_kernel<<<512, 256, 0, stream>>>(agg, x, stats, N);
  const int chunk = (N + 511) / 512;
  node_finish<<<512, 256, 0, stream>>>(stats, bn_w, bn_b, agg, x, batch, ln_w,
                                       ln_b, add_pool, counts, N, chunk);
  graph_out<<<1, 1024, 0, stream>>>(add_pool, counts, Wl, bl, w4, b4,
                                    (float*)d_out, G);
}

// Round 12
// 371.024 us; speedup vs baseline: 1.0594x; 1.0264x over previous
//
#include <hip/hip_runtime.h>
#include <math.h>

#define EPSF 1e-5f

typedef short bf16x8 __attribute__((ext_vector_type(8)));
typedef float f32x4 __attribute__((ext_vector_type(4)));

static __device__ __forceinline__ unsigned short f2bf(float x) {
  unsigned u = __float_as_uint(x);
  unsigned r = (u + 0x7FFFu + ((u >> 16) & 1u)) >> 16;
  return (unsigned short)r;
}

static __device__ __forceinline__ float msgv(float F, float S) {
  float sig = __builtin_amdgcn_rcpf(1.0f + __expf(-F));
  float sp = fmaxf(S, 0.f) + __logf(1.0f + __expf(-fabsf(S)));
  return sig * sp;
}

// ---------------- Prep (fused): cvt_x | bpack_edge(K=96) | bpack_node | hist --
__global__ __launch_bounds__(256) void prep_kernel(
    const float* __restrict__ x, const float* __restrict__ Wf,
    const float* __restrict__ Ws, const int* __restrict__ ei,
    unsigned short* __restrict__ xbf, unsigned short* __restrict__ Bfrag,
    unsigned short* __restrict__ Bfrag2, int* __restrict__ deg, int NCV,
    int total8, int E) {
  const int b = blockIdx.x, t = threadIdx.x;
  if (b < NCV) {
    int i = b * 256 + t;
    if (i < total8) {
      float4 a = ((const float4*)x)[i * 2];
      float4 c = ((const float4*)x)[i * 2 + 1];
      unsigned short o[8];
      o[0] = f2bf(a.x); o[1] = f2bf(a.y); o[2] = f2bf(a.z); o[3] = f2bf(a.w);
      o[4] = f2bf(c.x); o[5] = f2bf(c.y); o[6] = f2bf(c.z); o[7] = f2bf(c.w);
      ((uint4*)xbf)[i] = *(uint4*)o;
    }
  } else if (b < NCV + 6) {
    int g2 = (b - NCV) * 256 + t;
    if (g2 < 1536) {
      const int ks = g2 >> 9, t8 = (g2 >> 6) & 7, l = g2 & 63;
      const int q = l & 15, g = l >> 4;
      const float* W = (t8 < 4) ? Wf : Ws;
      const int col = (t8 & 3) * 16 + q;
      unsigned short out[8];
#pragma unroll
      for (int i = 0; i < 8; ++i) {
        int kk = ks * 32 + g * 8 + i;
        int wr = (kk < 32) ? (128 + kk) : (32 + kk);
        out[i] = f2bf(W[(size_t)wr * 64 + col]);
      }
      *(uint4*)&Bfrag[((size_t)(ks * 8 + t8) * 64 + l) * 8] = *(uint4*)out;
    }
  } else if (b < NCV + 10) {
    int g2 = (b - NCV - 6) * 256 + t;
    if (g2 < 1024) {
      const int ks = g2 >> 9, t8 = (g2 >> 6) & 7, l = g2 & 63;
      const int q = l & 15, g = l >> 4;
      const float* W = (t8 < 4) ? Wf : Ws;
      const int col = (t8 & 3) * 16 + q;
      unsigned short out[8];
#pragma unroll
      for (int i = 0; i < 8; ++i) {
        int kk = ks * 32 + g * 8 + i;
        out[i] = f2bf(W[(size_t)kk * 64 + col]);
      }
      *(uint4*)&Bfrag2[((size_t)(ks * 8 + t8) * 64 + l) * 8] = *(uint4*)out;
    }
  } else {
    int i = (b - NCV - 10) * 256 + t;
    if (i < E) atomicAdd(&deg[ei[E + i]], 1);
  }
}

// ---------------- K1: Pd[n][f] = pack_bf16(x@Wf_i + bf, x@Ws_i + bs) ---------
__global__ __launch_bounds__(256, 4) void node_mfma(
    const unsigned short* __restrict__ xbf,
    const unsigned short* __restrict__ Bfrag2, const float* __restrict__ bf_,
    const float* __restrict__ bs_, unsigned* __restrict__ Pd, int N) {
  __shared__ __align__(16) short Bsh[16][64][8];  // 16 KB
  for (int i = threadIdx.x; i < 1024; i += 256)
    ((uint4*)Bsh)[i] = ((const uint4*)Bfrag2)[i];
  __syncthreads();
  const int lane = threadIdx.x & 63, w = threadIdx.x >> 6;
  const int q = lane & 15, g = lane >> 4;
  const int row0 = blockIdx.x * 64;
  const float bfv = bf_[w * 16 + q], bsv = bs_[w * 16 + q];
  f32x4 accf[4], accs[4];
#pragma unroll
  for (int mt = 0; mt < 4; ++mt) {
    accf[mt] = (f32x4){0.f, 0.f, 0.f, 0.f};
    accs[mt] = (f32x4){0.f, 0.f, 0.f, 0.f};
  }
#pragma unroll
  for (int ks = 0; ks < 2; ++ks) {
    const bf16x8 Bfr = *(const bf16x8*)&Bsh[ks * 8 + w][lane][0];
    const bf16x8 Bsr = *(const bf16x8*)&Bsh[ks * 8 + 4 + w][lane][0];
#pragma unroll
    for (int mt = 0; mt < 4; ++mt) {
      int row = min(row0 + mt * 16 + q, N - 1);
      const bf16x8 a = *(const bf16x8*)(xbf + (size_t)row * 64 + ks * 32 + g * 8);
      accf[mt] = __builtin_amdgcn_mfma_f32_16x16x32_bf16(a, Bfr, accf[mt], 0, 0, 0);
      accs[mt] = __builtin_amdgcn_mfma_f32_16x16x32_bf16(a, Bsr, accs[mt], 0, 0, 0);
    }
  }
#pragma unroll
  for (int mt = 0; mt < 4; ++mt) {
#pragma unroll
    for (int r = 0; r < 4; ++r) {
      int row = row0 + mt * 16 + g * 4 + r;
      if (row < N) {
        unsigned u = ((unsigned)f2bf(accf[mt][r] + bfv) << 16) |
                     (unsigned)f2bf(accs[mt][r] + bsv);
        Pd[(size_t)row * 64 + w * 16 + q] = u;
      }
    }
  }
}

// ---------------- CSR build: 3-phase parallel exclusive scan ----------------
__global__ __launch_bounds__(256) void scan_a(const int* __restrict__ deg,
                                              int* __restrict__ bsum, int N) {
  const int idx = blockIdx.x * 256 + threadIdx.x;
  int v = (idx < N) ? deg[idx] : 0;
#pragma unroll
  for (int o = 32; o > 0; o >>= 1) v += __shfl_down(v, o);
  __shared__ int ws4[4];
  if ((threadIdx.x & 63) == 0) ws4[threadIdx.x >> 6] = v;
  __syncthreads();
  if (threadIdx.x == 0) bsum[blockIdx.x] = ws4[0] + ws4[1] + ws4[2] + ws4[3];
}

__global__ __launch_bounds__(256) void scan_b(const int* __restrict__ bsum,
                                              int* __restrict__ bpre, int NB) {
  const int t = threadIdx.x;
  const int lane = t & 63, w = t >> 6;
  int v = (t < NB) ? bsum[t] : 0;
  int sc = v;
#pragma unroll
  for (int o = 1; o < 64; o <<= 1) {
    int u = __shfl_up(sc, o);
    if (lane >= o) sc += u;
  }
  __shared__ int wsum[4];
  if (lane == 63) wsum[w] = sc;
  __syncthreads();
  int add = 0;
#pragma unroll
  for (int k = 0; k < 4; ++k) add += (k < w) ? wsum[k] : 0;
  bpre[t] = (sc - v) + add;
}

__global__ __launch_bounds__(256) void scan_c(const int* __restrict__ deg,
                                              const int* __restrict__ bpre,
                                              int* __restrict__ cursor, int N) {
  const int t = threadIdx.x;
  const int lane = t & 63, w = t >> 6;
  const int idx = blockIdx.x * 256 + t;
  int d = (idx < N) ? deg[idx] : 0;
  int sc = d;
#pragma unroll
  for (int o = 1; o < 64; o <<= 1) {
    int u = __shfl_up(sc, o);
    if (lane >= o) sc += u;
  }
  __shared__ int wsum[4];
  if (lane == 63) wsum[w] = sc;
  __syncthreads();
  int add = bpre[blockIdx.x];
#pragma unroll
  for (int k = 0; k < 4; ++k) add += (k < w) ? wsum[k] : 0;
  if (idx < N) cursor[idx] = add + (sc - d);
}

// ---------------- CSR build: scatter (edge_id, src, dst) --------------------
__global__ void scatter_kernel(const int* __restrict__ ei,
                               int* __restrict__ cursor,
                               int4* __restrict__ epair4, int E) {
  int i = blockIdx.x * 256 + threadIdx.x;
  if (i >= E) return;
  int dst = ei[E + i];
  int pos = atomicAdd(&cursor[dst], 1);
  epair4[pos] = make_int4(i, ei[i], dst, 0);
}

// ---------------- K2: barrier-free edge kernel, one WAVE per 16-edge tile ----
// A(16x96 bf16) = [eattr(direct fp32 gather + cvt) | x_src(bf16)] in registers.
// B(96x128) in LDS. Pd = packed bf16 (pf|ps) per (node,feat), L2-resident.
// Fast path (tile = one node): cross-g butterfly + one wave atomic (256B).
// Slow path: per-lane run-compressed atomics. No barriers in the loop.
__global__ __launch_bounds__(256, 4) void edge_fused(
    const int4* __restrict__ epair4, const float* __restrict__ eattr,
    const unsigned short* __restrict__ xbf,
    const unsigned short* __restrict__ Bfrag, const unsigned* __restrict__ Pd,
    float* __restrict__ agg, int T16, int N, int E) {
  __shared__ __align__(16) short Bsh[24][64][8];  // 24 KB
  for (int i = threadIdx.x; i < 1536; i += 256)
    ((uint4*)Bsh)[i] = ((const uint4*)Bfrag)[i];
  __syncthreads();

  const int lane = threadIdx.x & 63, w = threadIdx.x >> 6;
  const int q = lane & 15, g = lane >> 4;

  // XCD-grouped contiguous tile range per block; waves stride by 4 within it.
  const int nB = gridDim.x;
  const int cb = (blockIdx.x & 7) * (nB >> 3) + (blockIdx.x >> 3);
  const int q8 = T16 / nB, r8 = T16 - q8 * nB;
  const int t0 = cb * q8 + min(cb, r8);
  const int t1 = t0 + q8 + (cb < r8 ? 1 : 0);

  int t = t0 + w;
  if (t >= t1) return;

  int4 p = epair4[(size_t)t * 16 + q];
  unsigned exi = min((unsigned)p.x, (unsigned)(E - 1));
  float4 eA = *(const float4*)(eattr + (size_t)exi * 32 + g * 8);
  float4 eB = *(const float4*)(eattr + (size_t)exi * 32 + g * 8 + 4);
  unsigned su = min((unsigned)p.y, (unsigned)(N - 1));
  bf16x8 aX0 = *(const bf16x8*)(xbf + (size_t)su * 64 + g * 8);
  bf16x8 aX1 = *(const bf16x8*)(xbf + (size_t)su * 64 + 32 + g * 8);

  while (true) {
    const int tn = t + 4;
    const bool more = (tn < t1);
    int4 pn = p;
    float4 eAn = eA, eBn = eB;
    bf16x8 aX0n = aX0, aX1n = aX1;
    if (more) {  // register prefetch of next tile
      pn = epair4[(size_t)tn * 16 + q];
      unsigned exn = min((unsigned)pn.x, (unsigned)(E - 1));
      eAn = *(const float4*)(eattr + (size_t)exn * 32 + g * 8);
      eBn = *(const float4*)(eattr + (size_t)exn * 32 + g * 8 + 4);
      unsigned sn = min((unsigned)pn.y, (unsigned)(N - 1));
      aX0n = *(const bf16x8*)(xbf + (size_t)sn * 64 + g * 8);
      aX1n = *(const bf16x8*)(xbf + (size_t)sn * 64 + 32 + g * 8);
    }

    // convert eattr slice to bf16 A-fragment
    bf16x8 aE;
    aE[0] = (short)f2bf(eA.x); aE[1] = (short)f2bf(eA.y);
    aE[2] = (short)f2bf(eA.z); aE[3] = (short)f2bf(eA.w);
    aE[4] = (short)f2bf(eB.x); aE[5] = (short)f2bf(eB.y);
    aE[6] = (short)f2bf(eB.z); aE[7] = (short)f2bf(eB.w);

    // ---- 24 MFMA: 8 col-tiles (4 f + 4 s) x 3 K-slabs ----
    f32x4 accf[4], accs[4];
#pragma unroll
    for (int nt = 0; nt < 4; ++nt) {
      f32x4 z = {0.f, 0.f, 0.f, 0.f};
      accf[nt] = __builtin_amdgcn_mfma_f32_16x16x32_bf16(
          aE, *(const bf16x8*)&Bsh[nt][lane][0], z, 0, 0, 0);
      accf[nt] = __builtin_amdgcn_mfma_f32_16x16x32_bf16(
          aX0, *(const bf16x8*)&Bsh[8 + nt][lane][0], accf[nt], 0, 0, 0);
      accf[nt] = __builtin_amdgcn_mfma_f32_16x16x32_bf16(
          aX1, *(const bf16x8*)&Bsh[16 + nt][lane][0], accf[nt], 0, 0, 0);
      f32x4 z2 = {0.f, 0.f, 0.f, 0.f};
      accs[nt] = __builtin_amdgcn_mfma_f32_16x16x32_bf16(
          aE, *(const bf16x8*)&Bsh[4 + nt][lane][0], z2, 0, 0, 0);
      accs[nt] = __builtin_amdgcn_mfma_f32_16x16x32_bf16(
          aX0, *(const bf16x8*)&Bsh[12 + nt][lane][0], accs[nt], 0, 0, 0);
      accs[nt] = __builtin_amdgcn_mfma_f32_16x16x32_bf16(
          aX1, *(const bf16x8*)&Bsh[20 + nt][lane][0], accs[nt], 0, 0, 0);
    }

    // ---- epilogue ----
    const int dA = __shfl(p.z, 0);
    const int dB = __shfl(p.z, 15);
    if (dA == dB) {
      // whole tile is one node: butterfly + single wave atomic (256B)
      const unsigned du = min((unsigned)dA, (unsigned)(N - 1));
      float tot0, tot1, tot2, tot3;
#pragma unroll
      for (int cg = 0; cg < 4; ++cg) {
        unsigned pdw = Pd[(size_t)du * 64 + cg * 16 + q];
        float pf = __uint_as_float(pdw & 0xFFFF0000u);
        float ps = __uint_as_float(pdw << 16);
        float s = msgv(accf[cg][0] + pf, accs[cg][0] + ps) +
                  msgv(accf[cg][1] + pf, accs[cg][1] + ps) +
                  msgv(accf[cg][2] + pf, accs[cg][2] + ps) +
                  msgv(accf[cg][3] + pf, accs[cg][3] + ps);
        s += __shfl_xor(s, 16);
        s += __shfl_xor(s, 32);
        if (cg == 0) tot0 = s;
        else if (cg == 1) tot1 = s;
        else if (cg == 2) tot2 = s;
        else tot3 = s;
      }
      float v = (g == 0) ? tot0 : (g == 1) ? tot1 : (g == 2) ? tot2 : tot3;
      if ((unsigned)dA < (unsigned)N)
        atomicAdd(&agg[(size_t)dA * 64 + g * 16 + q], v);
    } else {
      // per-lane run-compressed walk (lane owns edges g*4..g*4+3)
      const int d0 = __shfl(p.z, g * 4);
      const int d1 = __shfl(p.z, g * 4 + 1);
      const int d2 = __shfl(p.z, g * 4 + 2);
      const int d3 = __shfl(p.z, g * 4 + 3);
#pragma unroll
      for (int cg = 0; cg < 4; ++cg) {
        const int feat = cg * 16 + q;
        const unsigned* Pr = Pd + feat;
        unsigned dc = (unsigned)d0;
        unsigned dl = min(dc, (unsigned)(N - 1));
        unsigned pdw = Pr[(size_t)dl * 64];
        float pf = __uint_as_float(pdw & 0xFFFF0000u);
        float ps = __uint_as_float(pdw << 16);
        float a_ = msgv(accf[cg][0] + pf, accs[cg][0] + ps);
#define STEP(DR, RIDX)                                                        \
  {                                                                           \
    unsigned dr = (unsigned)(DR);                                             \
    if (dr != dc) {                                                           \
      if (dc < (unsigned)N) atomicAdd(&agg[(size_t)dc * 64 + feat], a_);      \
      dc = dr; dl = min(dc, (unsigned)(N - 1));                               \
      pdw = Pr[(size_t)dl * 64];                                              \
      pf = __uint_as_float(pdw & 0xFFFF0000u);                                \
      ps = __uint_as_float(pdw << 16);                                        \
      a_ = 0.f;                                                               \
    }                                                                         \
    a_ += msgv(accf[cg][RIDX] + pf, accs[cg][RIDX] + ps);                     \
  }
        STEP(d1, 1)
        STEP(d2, 2)
        STEP(d3, 3)
#undef STEP
        if (dc < (unsigned)N) atomicAdd(&agg[(size_t)dc * 64 + feat], a_);
      }
    }

    if (!more) break;
    p = pn; eA = eAn; eB = eBn; aX0 = aX0n; aX1 = aX1n; t = tn;
  }
}

// ---------------- K3: per-feature reductions over agg and x ----------------
__global__ __launch_bounds__(256) void stats_kernel(
    const float* __restrict__ agg, const float* __restrict__ x,
    float* __restrict__ stats, int N) {
  const int f = threadIdx.x & 63;
  const int sub = threadIdx.x >> 6;
  float sa = 0, sa2 = 0, sx = 0, sx2 = 0, sax = 0;
  for (int r = blockIdx.x * 4 + sub; r < N; r += gridDim.x * 4) {
    float a = agg[(size_t)r * 64 + f];
    float xv = x[(size_t)r * 64 + f];
    sa += a; sa2 += a * a; sx += xv; sx2 += xv * xv; sax += a * xv;
  }
  __shared__ float lds[4][5][64];
  lds[sub][0][f] = sa; lds[sub][1][f] = sa2; lds[sub][2][f] = sx;
  lds[sub][3][f] = sx2; lds[sub][4][f] = sax;
  __syncthreads();
  if (sub == 0) {
#pragma unroll
    for (int i = 0; i < 5; ++i) {
      float v = lds[0][i][f] + lds[1][i][f] + lds[2][i][f] + lds[3][i][f];
      atomicAdd(&stats[i * 64 + f], v);
    }
  }
}

// ---------------- K5: finalize + BN+res+LN+softplus + pooling ----------------
__global__ __launch_bounds__(256) void node_finish(
    const float* __restrict__ stats, const float* __restrict__ bn_w,
    const float* __restrict__ bn_b, const float* __restrict__ agg,
    const float* __restrict__ x, const int* __restrict__ batch,
    const float* __restrict__ ln_w, const float* __restrict__ ln_b,
    float* __restrict__ add_pool, float* __restrict__ counts, int N,
    int chunk) {
  const int f = threadIdx.x & 63;
  const int sub = threadIdx.x >> 6;
  const float Nf = (float)N;
  const float invN = 1.0f / Nf;
  float Sa = stats[f], Sa2 = stats[64 + f], Sx = stats[128 + f],
        Sx2 = stats[192 + f], Sax = stats[256 + f];
  float mu = Sa * invN;
  float var = Sa2 * invN - mu * mu;
  const float alpha = bn_w[f] / sqrtf(var + EPSF);
  const float beta = bn_b[f] - mu * alpha;
  float Sh = alpha * Sa + Nf * beta + Sx;
  float Sh2 = alpha * alpha * Sa2 + Sx2 + Nf * beta * beta +
              2.f * alpha * Sax + 2.f * alpha * beta * Sa + 2.f * beta * Sx;
#pragma unroll
  for (int o = 32; o > 0; o >>= 1) {
    Sh += __shfl_xor(Sh, o);
    Sh2 += __shfl_xor(Sh2, o);
  }
  const float cnt = Nf * 64.0f;
  const float mean = Sh / cnt;
  const float msq = Sh2 / cnt - mean * mean;
  const float rden = 1.0f / (sqrtf(fmaxf(msq, 0.f)) + EPSF);
  const float lw = ln_w[f] * rden;
  const float lb = ln_b[f];

  const int r0 = blockIdx.x * chunk;
  const int r1 = min(N, r0 + chunk);
  float acc = 0.f, cacc = 0.f;
  int curg = -1;
  for (int r = r0 + sub; r < r1; r += 4) {
    int g = batch[r];
    if (g != curg) {
      if (curg >= 0) {
        atomicAdd(&add_pool[(size_t)curg * 64 + f], acc);
        if (f == 0) atomicAdd(&counts[curg], cacc);
      }
      curg = g; acc = 0.f; cacc = 0.f;
    }
    float h = fmaf(alpha, agg[(size_t)r * 64 + f], beta) + x[(size_t)r * 64 + f];
    float v = (h - mean) * lw + lb;
    float sp = fmaxf(v, 0.f) + __logf(1.0f + __expf(-fabsf(v)));
    acc += sp; cacc += 1.f;
  }
  if (curg >= 0) {
    atomicAdd(&add_pool[(size_t)curg * 64 + f], acc);
    if (f == 0) atomicAdd(&counts[curg], cacc);
  }
}

// ---------------- K6: graph head (vectorized) ----------------
__global__ __launch_bounds__(1024) void graph_out(
    const float* __restrict__ add_pool, const float* __restrict__ counts,
    const float* __restrict__ Wl, const float* __restrict__ bl,
    const float* __restrict__ w4, const float* __restrict__ b4,
    float* __restrict__ out, int G) {
  const int t = threadIdx.x;
  const int g = t >> 1, c = t & 1;
  float cnt = fmaxf(counts[g], 1.0f);
  float inv = 1.0f / cnt;
  const float4* ap4 = (const float4*)(add_pool + (size_t)g * 64);
  const float4* W4 = (const float4*)Wl;
  float v = bl[c];
#pragma unroll 4
  for (int k4 = 0; k4 < 16; ++k4) {
    float4 a4 = ap4[k4];
    float4 wa = W4[k4 * 2];
    float4 wb = W4[k4 * 2 + 1];
    float4 wc = W4[32 + k4 * 2];
    float4 wd = W4[32 + k4 * 2 + 1];
    float m0 = c ? wa.y : wa.x, m1 = c ? wa.w : wa.z;
    float m2 = c ? wb.y : wb.x, m3 = c ? wb.w : wb.z;
    float a0 = c ? wc.y : wc.x, a1 = c ? wc.w : wc.z;
    float a2 = c ? wd.y : wd.x, a3 = c ? wd.w : wd.z;
    v = fmaf(a4.x, fmaf(m0, inv, a0), v);
    v = fmaf(a4.y, fmaf(m1, inv, a1), v);
    v = fmaf(a4.z, fmaf(m2, inv, a2), v);
    v = fmaf(a4.w, fmaf(m3, inv, a3), v);
  }

  __shared__ float red[16];
  __shared__ float bc[2];
  float sum = v;
#pragma unroll
  for (int o = 32; o > 0; o >>= 1) sum += __shfl_down(sum, o);
  if ((t & 63) == 0) red[t >> 6] = sum;
  __syncthreads();
  if (t == 0) {
    float tot = 0;
#pragma unroll
    for (int i = 0; i < 16; ++i) tot += red[i];
    bc[0] = tot * (1.0f / 1024.0f);
  }
  __syncthreads();
  const float mean = bc[0];
  const float xc = v - mean;
  float sq = xc * xc;
  __syncthreads();
#pragma unroll
  for (int o = 32; o > 0; o >>= 1) sq += __shfl_down(sq, o);
  if ((t & 63) == 0) red[t >> 6] = sq;
  __syncthreads();
  if (t == 0) {
    float tot = 0;
#pragma unroll
    for (int i = 0; i < 16; ++i) tot += red[i];
    bc[1] = 1.0f / (sqrtf(tot * (1.0f / 1024.0f)) + EPSF);
  }
  __syncthreads();
  out[t] = xc * bc[1] * w4[c] + b4[c];
}

extern "C" void kernel_launch(void* const* d_in, const int* in_sizes, int n_in,
                              void* d_out, int out_size, void* d_ws,
                              size_t ws_size, hipStream_t stream) {
  const float* x = (const float*)d_in[0];
  const int* ei = (const int*)d_in[1];
  const float* eattr = (const float*)d_in[2];
  const int* batch = (const int*)d_in[3];
  const float* Wf = (const float*)d_in[4];
  const float* bf = (const float*)d_in[5];
  const float* Ws = (const float*)d_in[6];
  const float* bs = (const float*)d_in[7];
  const float* bn_w = (const float*)d_in[8];
  const float* bn_b = (const float*)d_in[9];
  const float* ln_w = (const float*)d_in[10];
  const float* ln_b = (const float*)d_in[11];
  const float* Wl = (const float*)d_in[12];
  const float* bl = (const float*)d_in[13];
  const float* w4 = (const float*)d_in[14];
  const float* b4 = (const float*)d_in[15];

  const int N = in_sizes[0] / 64;
  const int E = in_sizes[2] / 32;
  const int G = 512;
  const int NB = (N + 255) / 256;
  const int T16 = (E + 15) / 16;
  const int NCV = (N * 8 + 255) / 256;
  const int NH = (E + 255) / 256;

  // Workspace layout (floats; each chunk multiple of 4 => 16B alignment).
  float* ws = (float*)d_ws;
  float* agg = ws;                                   // N*64  [zeroed]
  float* stats = agg + (size_t)N * 64;               // 320   [zeroed]
  float* add_pool = stats + 320;                     // G*64  [zeroed]
  float* counts = add_pool + (size_t)G * 64;         // G     [zeroed]
  int* deg = (int*)(counts + G);                     // N     [zeroed]
  int* cursor = deg + N;                             // N
  int* bsum = cursor + N;                            // 256
  int* bpre = bsum + 256;                            // 256
  unsigned short* Bfrag = (unsigned short*)(bpre + 256);   // 12288 ush (24KB)
  unsigned short* Bfrag2 = Bfrag + 12288;                  // 8192 ush (16KB)
  unsigned short* xbf = Bfrag2 + 8192;                     // N*64 ush
  unsigned* Pd = (unsigned*)(xbf + (size_t)N * 64);        // N*64 u32
  int4* epair4 = (int4*)(Pd + (size_t)N * 64);             // T16*16 int4

  size_t zeroFloats = (size_t)N * 64 + 320 + (size_t)G * 64 + G + N;
  hipMemsetAsync(agg, 0, zeroFloats * sizeof(float), stream);
  const int padE = T16 * 16 - E;
  if (padE > 0) hipMemsetAsync(epair4 + E, 0xFF, (size_t)padE * 16, stream);

  prep_kernel<<<NCV + 10 + NH, 256, 0, stream>>>(x, Wf, Ws, ei, xbf, Bfrag,
                                                 Bfrag2, deg, NCV, N * 8, E);
  node_mfma<<<(N + 63) / 64, 256, 0, stream>>>(xbf, Bfrag2, bf, bs, Pd, N);
  scan_a<<<NB, 256, 0, stream>>>(deg, bsum, N);
  scan_b<<<1, 256, 0, stream>>>(bsum, bpre, NB);
  scan_c<<<NB, 256, 0, stream>>>(deg, bpre, cursor, N);
  scatter_kernel<<<NH, 256, 0, stream>>>(ei, cursor, epair4, E);
  edge_fused<<<1024, 256, 0, stream>>>(epair4, eattr, xbf, Bfrag, Pd, agg, T16,
                                       N, E);
  stats_kernel<<<512, 256, 0, stream>>>(agg, x, stats, N);
  const int chunk = (N + 511) / 512;
  node_finish<<<512, 256, 0, stream>>>(stats, bn_w, bn_b, agg, x, batch, ln_w,
                                       ln_b, add_pool, counts, N, chunk);
  graph_out<<<1, 1024, 0, stream>>>(add_pool, counts, Wl, bl, w4, b4,
                                    (float*)d_out, G);
}

// Round 13
// 345.494 us; speedup vs baseline: 1.1377x; 1.0739x over previous
//
#include <hip/hip_runtime.h>
#include <math.h>

#define EPSF 1e-5f
#define WIN 56

typedef short bf16x8 __attribute__((ext_vector_type(8)));
typedef float f32x4 __attribute__((ext_vector_type(4)));

static __device__ __forceinline__ unsigned short f2bf(float x) {
  unsigned u = __float_as_uint(x);
  unsigned r = (u + 0x7FFFu + ((u >> 16) & 1u)) >> 16;
  return (unsigned short)r;
}

static __device__ __forceinline__ float msgv(float F, float S) {
  float sig = __builtin_amdgcn_rcpf(1.0f + __expf(-F));
  float sp = fmaxf(S, 0.f) + __logf(1.0f + __expf(-fabsf(S)));
  return sig * sp;
}

// ---------------- Prep (fused): cvt_x | bpack_edge(K=96) | bpack_node | hist --
__global__ __launch_bounds__(256) void prep_kernel(
    const float* __restrict__ x, const float* __restrict__ Wf,
    const float* __restrict__ Ws, const int* __restrict__ ei,
    unsigned short* __restrict__ xbf, unsigned short* __restrict__ Bfrag,
    unsigned short* __restrict__ Bfrag2, int* __restrict__ deg, int NCV,
    int total8, int E) {
  const int b = blockIdx.x, t = threadIdx.x;
  if (b < NCV) {
    int i = b * 256 + t;
    if (i < total8) {
      float4 a = ((const float4*)x)[i * 2];
      float4 c = ((const float4*)x)[i * 2 + 1];
      unsigned short o[8];
      o[0] = f2bf(a.x); o[1] = f2bf(a.y); o[2] = f2bf(a.z); o[3] = f2bf(a.w);
      o[4] = f2bf(c.x); o[5] = f2bf(c.y); o[6] = f2bf(c.z); o[7] = f2bf(c.w);
      ((uint4*)xbf)[i] = *(uint4*)o;
    }
  } else if (b < NCV + 6) {
    int g2 = (b - NCV) * 256 + t;
    if (g2 < 1536) {
      const int ks = g2 >> 9, t8 = (g2 >> 6) & 7, l = g2 & 63;
      const int q = l & 15, g = l >> 4;
      const float* W = (t8 < 4) ? Wf : Ws;
      const int col = (t8 & 3) * 16 + q;
      unsigned short out[8];
#pragma unroll
      for (int i = 0; i < 8; ++i) {
        int kk = ks * 32 + g * 8 + i;
        int wr = (kk < 32) ? (128 + kk) : (32 + kk);
        out[i] = f2bf(W[(size_t)wr * 64 + col]);
      }
      *(uint4*)&Bfrag[((size_t)(ks * 8 + t8) * 64 + l) * 8] = *(uint4*)out;
    }
  } else if (b < NCV + 10) {
    int g2 = (b - NCV - 6) * 256 + t;
    if (g2 < 1024) {
      const int ks = g2 >> 9, t8 = (g2 >> 6) & 7, l = g2 & 63;
      const int q = l & 15, g = l >> 4;
      const float* W = (t8 < 4) ? Wf : Ws;
      const int col = (t8 & 3) * 16 + q;
      unsigned short out[8];
#pragma unroll
      for (int i = 0; i < 8; ++i) {
        int kk = ks * 32 + g * 8 + i;
        out[i] = f2bf(W[(size_t)kk * 64 + col]);
      }
      *(uint4*)&Bfrag2[((size_t)(ks * 8 + t8) * 64 + l) * 8] = *(uint4*)out;
    }
  } else {
    int i = (b - NCV - 10) * 256 + t;
    if (i < E) atomicAdd(&deg[ei[E + i]], 1);
  }
}

// ---------------- K1: Pd[n][f] = pack_bf16(x@Wf_i + bf, x@Ws_i + bs) ---------
__global__ __launch_bounds__(256, 4) void node_mfma(
    const unsigned short* __restrict__ xbf,
    const unsigned short* __restrict__ Bfrag2, const float* __restrict__ bf_,
    const float* __restrict__ bs_, unsigned* __restrict__ Pd, int N) {
  __shared__ __align__(16) short Bsh[16][64][8];  // 16 KB
  for (int i = threadIdx.x; i < 1024; i += 256)
    ((uint4*)Bsh)[i] = ((const uint4*)Bfrag2)[i];
  __syncthreads();
  const int lane = threadIdx.x & 63, w = threadIdx.x >> 6;
  const int q = lane & 15, g = lane >> 4;
  const int row0 = blockIdx.x * 64;
  const float bfv = bf_[w * 16 + q], bsv = bs_[w * 16 + q];
  f32x4 accf[4], accs[4];
#pragma unroll
  for (int mt = 0; mt < 4; ++mt) {
    accf[mt] = (f32x4){0.f, 0.f, 0.f, 0.f};
    accs[mt] = (f32x4){0.f, 0.f, 0.f, 0.f};
  }
#pragma unroll
  for (int ks = 0; ks < 2; ++ks) {
    const bf16x8 Bfr = *(const bf16x8*)&Bsh[ks * 8 + w][lane][0];
    const bf16x8 Bsr = *(const bf16x8*)&Bsh[ks * 8 + 4 + w][lane][0];
#pragma unroll
    for (int mt = 0; mt < 4; ++mt) {
      int row = min(row0 + mt * 16 + q, N - 1);
      const bf16x8 a = *(const bf16x8*)(xbf + (size_t)row * 64 + ks * 32 + g * 8);
      accf[mt] = __builtin_amdgcn_mfma_f32_16x16x32_bf16(a, Bfr, accf[mt], 0, 0, 0);
      accs[mt] = __builtin_amdgcn_mfma_f32_16x16x32_bf16(a, Bsr, accs[mt], 0, 0, 0);
    }
  }
#pragma unroll
  for (int mt = 0; mt < 4; ++mt) {
#pragma unroll
    for (int r = 0; r < 4; ++r) {
      int row = row0 + mt * 16 + g * 4 + r;
      if (row < N) {
        unsigned u = ((unsigned)f2bf(accf[mt][r] + bfv) << 16) |
                     (unsigned)f2bf(accs[mt][r] + bsv);
        Pd[(size_t)row * 64 + w * 16 + q] = u;
      }
    }
  }
}

// ---------------- CSR build: 3-phase parallel exclusive scan ----------------
__global__ __launch_bounds__(256) void scan_a(const int* __restrict__ deg,
                                              int* __restrict__ bsum, int N) {
  const int idx = blockIdx.x * 256 + threadIdx.x;
  int v = (idx < N) ? deg[idx] : 0;
#pragma unroll
  for (int o = 32; o > 0; o >>= 1) v += __shfl_down(v, o);
  __shared__ int ws4[4];
  if ((threadIdx.x & 63) == 0) ws4[threadIdx.x >> 6] = v;
  __syncthreads();
  if (threadIdx.x == 0) bsum[blockIdx.x] = ws4[0] + ws4[1] + ws4[2] + ws4[3];
}

__global__ __launch_bounds__(256) void scan_b(const int* __restrict__ bsum,
                                              int* __restrict__ bpre, int NB) {
  const int t = threadIdx.x;
  const int lane = t & 63, w = t >> 6;
  int v = (t < NB) ? bsum[t] : 0;
  int sc = v;
#pragma unroll
  for (int o = 1; o < 64; o <<= 1) {
    int u = __shfl_up(sc, o);
    if (lane >= o) sc += u;
  }
  __shared__ int wsum[4];
  if (lane == 63) wsum[w] = sc;
  __syncthreads();
  int add = 0;
#pragma unroll
  for (int k = 0; k < 4; ++k) add += (k < w) ? wsum[k] : 0;
  bpre[t] = (sc - v) + add;
}

__global__ __launch_bounds__(256) void scan_c(const int* __restrict__ deg,
                                              const int* __restrict__ bpre,
                                              int* __restrict__ cursor, int N) {
  const int t = threadIdx.x;
  const int lane = t & 63, w = t >> 6;
  const int idx = blockIdx.x * 256 + t;
  int d = (idx < N) ? deg[idx] : 0;
  int sc = d;
#pragma unroll
  for (int o = 1; o < 64; o <<= 1) {
    int u = __shfl_up(sc, o);
    if (lane >= o) sc += u;
  }
  __shared__ int wsum[4];
  if (lane == 63) wsum[w] = sc;
  __syncthreads();
  int add = bpre[blockIdx.x];
#pragma unroll
  for (int k = 0; k < 4; ++k) add += (k < w) ? wsum[k] : 0;
  if (idx < N) cursor[idx] = add + (sc - d);
}

// ---------------- CSR build: scatter (eid, src|dst<<16) ---------------------
__global__ void scatter_kernel(const int* __restrict__ ei,
                               int* __restrict__ cursor,
                               int2* __restrict__ epair2, int E) {
  int i = blockIdx.x * 256 + threadIdx.x;
  if (i >= E) return;
  int dst = ei[E + i];
  int pos = atomicAdd(&cursor[dst], 1);
  epair2[pos] = make_int2(i, ei[i] | (dst << 16));
}

// ---------------- K2: barrier-free edge kernel + LDS node-window accum -------
// One WAVE per 16-edge tile; block owns a contiguous (dst-sorted) tile range.
// Messages accumulate into LDS msum[dst - dstBase] (window WIN nodes, covers
// ~49-node expected span); rare out-of-window dsts fall back to global
// atomics. One __syncthreads per BLOCK (not per tile), then flush touched
// rows with one global atomicAdd per (node,feat).
__global__ __launch_bounds__(256, 4) void edge_fused(
    const int2* __restrict__ epair2, const float* __restrict__ eattr,
    const unsigned short* __restrict__ xbf,
    const unsigned short* __restrict__ Bfrag, const unsigned* __restrict__ Pd,
    float* __restrict__ agg, int T16, int N, int E) {
  __shared__ __align__(16) short Bsh[24][64][8];  // 24 KB
  __shared__ float msum[WIN][64];                 // 14 KB
  __shared__ int touched[WIN];
  for (int i = threadIdx.x; i < 1536; i += 256)
    ((uint4*)Bsh)[i] = ((const uint4*)Bfrag)[i];
  for (int i = threadIdx.x; i < WIN * 64; i += 256) ((float*)msum)[i] = 0.f;
  for (int i = threadIdx.x; i < WIN; i += 256) touched[i] = 0;
  __syncthreads();

  const int lane = threadIdx.x & 63, w = threadIdx.x >> 6;
  const int q = lane & 15, g = lane >> 4;

  // XCD-grouped contiguous tile range per block; waves stride by 4 within it.
  const int nB = gridDim.x;
  const int cb = (blockIdx.x & 7) * (nB >> 3) + (blockIdx.x >> 3);
  const int q8 = T16 / nB, r8 = T16 - q8 * nB;
  const int t0 = cb * q8 + min(cb, r8);
  const int t1 = t0 + q8 + (cb < r8 ? 1 : 0);

  // block-uniform window base: dst of the block's first edge
  const int dstBase = (int)(((unsigned)epair2[(size_t)t0 * 16].y) >> 16);

#define FLUSH(DC, FEAT, VAL)                                                  \
  {                                                                           \
    int _idx = (int)(DC)-dstBase;                                             \
    if ((unsigned)_idx < (unsigned)WIN) {                                     \
      atomicAdd(&msum[_idx][FEAT], (VAL));                                    \
      touched[_idx] = 1;                                                      \
    } else if ((DC) < (unsigned)N) {                                          \
      atomicAdd(&agg[(size_t)(DC)*64 + (FEAT)], (VAL));                       \
    }                                                                         \
  }

  int t = t0 + w;
  if (t < t1) {
    int2 p = epair2[(size_t)t * 16 + q];
    unsigned exi = min((unsigned)p.x, (unsigned)(E - 1));
    float4 eA = *(const float4*)(eattr + (size_t)exi * 32 + g * 8);
    float4 eB = *(const float4*)(eattr + (size_t)exi * 32 + g * 8 + 4);
    unsigned su = min((unsigned)p.y & 0xFFFFu, (unsigned)(N - 1));
    bf16x8 aX0 = *(const bf16x8*)(xbf + (size_t)su * 64 + g * 8);
    bf16x8 aX1 = *(const bf16x8*)(xbf + (size_t)su * 64 + 32 + g * 8);

    while (true) {
      const int tn = t + 4;
      const bool more = (tn < t1);
      int2 pn = p;
      float4 eAn = eA, eBn = eB;
      bf16x8 aX0n = aX0, aX1n = aX1;
      if (more) {  // register prefetch of next tile
        pn = epair2[(size_t)tn * 16 + q];
        unsigned exn = min((unsigned)pn.x, (unsigned)(E - 1));
        eAn = *(const float4*)(eattr + (size_t)exn * 32 + g * 8);
        eBn = *(const float4*)(eattr + (size_t)exn * 32 + g * 8 + 4);
        unsigned sn = min((unsigned)pn.y & 0xFFFFu, (unsigned)(N - 1));
        aX0n = *(const bf16x8*)(xbf + (size_t)sn * 64 + g * 8);
        aX1n = *(const bf16x8*)(xbf + (size_t)sn * 64 + 32 + g * 8);
      }

      bf16x8 aE;
      aE[0] = (short)f2bf(eA.x); aE[1] = (short)f2bf(eA.y);
      aE[2] = (short)f2bf(eA.z); aE[3] = (short)f2bf(eA.w);
      aE[4] = (short)f2bf(eB.x); aE[5] = (short)f2bf(eB.y);
      aE[6] = (short)f2bf(eB.z); aE[7] = (short)f2bf(eB.w);

      // ---- 24 MFMA: 8 col-tiles (4 f + 4 s) x 3 K-slabs ----
      f32x4 accf[4], accs[4];
#pragma unroll
      for (int nt = 0; nt < 4; ++nt) {
        f32x4 z = {0.f, 0.f, 0.f, 0.f};
        accf[nt] = __builtin_amdgcn_mfma_f32_16x16x32_bf16(
            aE, *(const bf16x8*)&Bsh[nt][lane][0], z, 0, 0, 0);
        accf[nt] = __builtin_amdgcn_mfma_f32_16x16x32_bf16(
            aX0, *(const bf16x8*)&Bsh[8 + nt][lane][0], accf[nt], 0, 0, 0);
        accf[nt] = __builtin_amdgcn_mfma_f32_16x16x32_bf16(
            aX1, *(const bf16x8*)&Bsh[16 + nt][lane][0], accf[nt], 0, 0, 0);
        f32x4 z2 = {0.f, 0.f, 0.f, 0.f};
        accs[nt] = __builtin_amdgcn_mfma_f32_16x16x32_bf16(
            aE, *(const bf16x8*)&Bsh[4 + nt][lane][0], z2, 0, 0, 0);
        accs[nt] = __builtin_amdgcn_mfma_f32_16x16x32_bf16(
            aX0, *(const bf16x8*)&Bsh[12 + nt][lane][0], accs[nt], 0, 0, 0);
        accs[nt] = __builtin_amdgcn_mfma_f32_16x16x32_bf16(
            aX1, *(const bf16x8*)&Bsh[20 + nt][lane][0], accs[nt], 0, 0, 0);
      }

      // ---- epilogue ----
      const unsigned dA = ((unsigned)__shfl(p.y, 0)) >> 16;
      const unsigned dB = ((unsigned)__shfl(p.y, 15)) >> 16;
      if (dA == dB) {
        // whole tile one node: butterfly + single LDS/global add per lane
        const unsigned du = min(dA, (unsigned)(N - 1));
        float tot0, tot1, tot2, tot3;
#pragma unroll
        for (int cg = 0; cg < 4; ++cg) {
          unsigned pdw = Pd[(size_t)du * 64 + cg * 16 + q];
          float pf = __uint_as_float(pdw & 0xFFFF0000u);
          float ps = __uint_as_float(pdw << 16);
          float s = msgv(accf[cg][0] + pf, accs[cg][0] + ps) +
                    msgv(accf[cg][1] + pf, accs[cg][1] + ps) +
                    msgv(accf[cg][2] + pf, accs[cg][2] + ps) +
                    msgv(accf[cg][3] + pf, accs[cg][3] + ps);
          s += __shfl_xor(s, 16);
          s += __shfl_xor(s, 32);
          if (cg == 0) tot0 = s;
          else if (cg == 1) tot1 = s;
          else if (cg == 2) tot2 = s;
          else tot3 = s;
        }
        float v = (g == 0) ? tot0 : (g == 1) ? tot1 : (g == 2) ? tot2 : tot3;
        FLUSH(dA, g * 16 + q, v);
      } else {
        const unsigned d0 = ((unsigned)__shfl(p.y, g * 4)) >> 16;
        const unsigned d1 = ((unsigned)__shfl(p.y, g * 4 + 1)) >> 16;
        const unsigned d2 = ((unsigned)__shfl(p.y, g * 4 + 2)) >> 16;
        const unsigned d3 = ((unsigned)__shfl(p.y, g * 4 + 3)) >> 16;
#pragma unroll
        for (int cg = 0; cg < 4; ++cg) {
          const int feat = cg * 16 + q;
          const unsigned* Pr = Pd + feat;
          unsigned dc = d0;
          unsigned dl = min(dc, (unsigned)(N - 1));
          unsigned pdw = Pr[(size_t)dl * 64];
          float pf = __uint_as_float(pdw & 0xFFFF0000u);
          float ps = __uint_as_float(pdw << 16);
          float a_ = msgv(accf[cg][0] + pf, accs[cg][0] + ps);
#define STEP(DR, RIDX)                                                        \
  {                                                                           \
    unsigned dr = (DR);                                                       \
    if (dr != dc) {                                                           \
      FLUSH(dc, feat, a_);                                                    \
      dc = dr; dl = min(dc, (unsigned)(N - 1));                               \
      pdw = Pr[(size_t)dl * 64];                                              \
      pf = __uint_as_float(pdw & 0xFFFF0000u);                                \
      ps = __uint_as_float(pdw << 16);                                        \
      a_ = 0.f;                                                               \
    }                                                                         \
    a_ += msgv(accf[cg][RIDX] + pf, accs[cg][RIDX] + ps);                     \
  }
          STEP(d1, 1)
          STEP(d2, 2)
          STEP(d3, 3)
#undef STEP
          FLUSH(dc, feat, a_);
        }
      }

      if (!more) break;
      p = pn; eA = eAn; eB = eBn; aX0 = aX0n; aX1 = aX1n; t = tn;
    }
  }

  // ---- block flush: one global atomic per touched (node,feat) ----
  __syncthreads();
  for (int n = w; n < WIN; n += 4) {
    if (touched[n]) {
      unsigned dn = (unsigned)(dstBase + n);
      if (dn < (unsigned)N) atomicAdd(&agg[(size_t)dn * 64 + lane], msum[n][lane]);
    }
  }
#undef FLUSH
}

// ---------------- K3: per-feature reductions over agg and x ----------------
__global__ __launch_bounds__(256) void stats_kernel(
    const float* __restrict__ agg, const float* __restrict__ x,
    float* __restrict__ stats, int N) {
  const int f = threadIdx.x & 63;
  const int sub = threadIdx.x >> 6;
  float sa = 0, sa2 = 0, sx = 0, sx2 = 0, sax = 0;
  for (int r = blockIdx.x * 4 + sub; r < N; r += gridDim.x * 4) {
    float a = agg[(size_t)r * 64 + f];
    float xv = x[(size_t)r * 64 + f];
    sa += a; sa2 += a * a; sx += xv; sx2 += xv * xv; sax += a * xv;
  }
  __shared__ float lds[4][5][64];
  lds[sub][0][f] = sa; lds[sub][1][f] = sa2; lds[sub][2][f] = sx;
  lds[sub][3][f] = sx2; lds[sub][4][f] = sax;
  __syncthreads();
  if (sub == 0) {
#pragma unroll
    for (int i = 0; i < 5; ++i) {
      float v = lds[0][i][f] + lds[1][i][f] + lds[2][i][f] + lds[3][i][f];
      atomicAdd(&stats[i * 64 + f], v);
    }
  }
}

// ---------------- K5: finalize + BN+res+LN+softplus + pooling ----------------
__global__ __launch_bounds__(256) void node_finish(
    const float* __restrict__ stats, const float* __restrict__ bn_w,
    const float* __restrict__ bn_b, const float* __restrict__ agg,
    const float* __restrict__ x, const int* __restrict__ batch,
    const float* __restrict__ ln_w, const float* __restrict__ ln_b,
    float* __restrict__ add_pool, float* __restrict__ counts, int N,
    int chunk) {
  const int f = threadIdx.x & 63;
  const int sub = threadIdx.x >> 6;
  const float Nf = (float)N;
  const float invN = 1.0f / Nf;
  float Sa = stats[f], Sa2 = stats[64 + f], Sx = stats[128 + f],
        Sx2 = stats[192 + f], Sax = stats[256 + f];
  float mu = Sa * invN;
  float var = Sa2 * invN - mu * mu;
  const float alpha = bn_w[f] / sqrtf(var + EPSF);
  const float beta = bn_b[f] - mu * alpha;
  float Sh = alpha * Sa + Nf * beta + Sx;
  float Sh2 = alpha * alpha * Sa2 + Sx2 + Nf * beta * beta +
              2.f * alpha * Sax + 2.f * alpha * beta * Sa + 2.f * beta * Sx;
#pragma unroll
  for (int o = 32; o > 0; o >>= 1) {
    Sh += __shfl_xor(Sh, o);
    Sh2 += __shfl_xor(Sh2, o);
  }
  const float cnt = Nf * 64.0f;
  const float mean = Sh / cnt;
  const float msq = Sh2 / cnt - mean * mean;
  const float rden = 1.0f / (sqrtf(fmaxf(msq, 0.f)) + EPSF);
  const float lw = ln_w[f] * rden;
  const float lb = ln_b[f];

  const int r0 = blockIdx.x * chunk;
  const int r1 = min(N, r0 + chunk);
  float acc = 0.f, cacc = 0.f;
  int curg = -1;
  for (int r = r0 + sub; r < r1; r += 4) {
    int g = batch[r];
    if (g != curg) {
      if (curg >= 0) {
        atomicAdd(&add_pool[(size_t)curg * 64 + f], acc);
        if (f == 0) atomicAdd(&counts[curg], cacc);
      }
      curg = g; acc = 0.f; cacc = 0.f;
    }
    float h = fmaf(alpha, agg[(size_t)r * 64 + f], beta) + x[(size_t)r * 64 + f];
    float v = (h - mean) * lw + lb;
    float sp = fmaxf(v, 0.f) + __logf(1.0f + __expf(-fabsf(v)));
    acc += sp; cacc += 1.f;
  }
  if (curg >= 0) {
    atomicAdd(&add_pool[(size_t)curg * 64 + f], acc);
    if (f == 0) atomicAdd(&counts[curg], cacc);
  }
}

// ---------------- K6: graph head (vectorized) ----------------
__global__ __launch_bounds__(1024) void graph_out(
    const float* __restrict__ add_pool, const float* __restrict__ counts,
    const float* __restrict__ Wl, const float* __restrict__ bl,
    const float* __restrict__ w4, const float* __restrict__ b4,
    float* __restrict__ out, int G) {
  const int t = threadIdx.x;
  const int g = t >> 1, c = t & 1;
  float cnt = fmaxf(counts[g], 1.0f);
  float inv = 1.0f / cnt;
  const float4* ap4 = (const float4*)(add_pool + (size_t)g * 64);
  const float4* W4 = (const float4*)Wl;
  float v = bl[c];
#pragma unroll 4
  for (int k4 = 0; k4 < 16; ++k4) {
    float4 a4 = ap4[k4];
    float4 wa = W4[k4 * 2];
    float4 wb = W4[k4 * 2 + 1];
    float4 wc = W4[32 + k4 * 2];
    float4 wd = W4[32 + k4 * 2 + 1];
    float m0 = c ? wa.y : wa.x, m1 = c ? wa.w : wa.z;
    float m2 = c ? wb.y : wb.x, m3 = c ? wb.w : wb.z;
    float a0 = c ? wc.y : wc.x, a1 = c ? wc.w : wc.z;
    float a2 = c ? wd.y : wd.x, a3 = c ? wd.w : wd.z;
    v = fmaf(a4.x, fmaf(m0, inv, a0), v);
    v = fmaf(a4.y, fmaf(m1, inv, a1), v);
    v = fmaf(a4.z, fmaf(m2, inv, a2), v);
    v = fmaf(a4.w, fmaf(m3, inv, a3), v);
  }

  __shared__ float red[16];
  __shared__ float bc[2];
  float sum = v;
#pragma unroll
  for (int o = 32; o > 0; o >>= 1) sum += __shfl_down(sum, o);
  if ((t & 63) == 0) red[t >> 6] = sum;
  __syncthreads();
  if (t == 0) {
    float tot = 0;
#pragma unroll
    for (int i = 0; i < 16; ++i) tot += red[i];
    bc[0] = tot * (1.0f / 1024.0f);
  }
  __syncthreads();
  const float mean = bc[0];
  const float xc = v - mean;
  float sq = xc * xc;
  __syncthreads();
#pragma unroll
  for (int o = 32; o > 0; o >>= 1) sq += __shfl_down(sq, o);
  if ((t & 63) == 0) red[t >> 6] = sq;
  __syncthreads();
  if (t == 0) {
    float tot = 0;
#pragma unroll
    for (int i = 0; i < 16; ++i) tot += red[i];
    bc[1] = 1.0f / (sqrtf(tot * (1.0f / 1024.0f)) + EPSF);
  }
  __syncthreads();
  out[t] = xc * bc[1] * w4[c] + b4[c];
}

extern "C" void kernel_launch(void* const* d_in, const int* in_sizes, int n_in,
                              void* d_out, int out_size, void* d_ws,
                              size_t ws_size, hipStream_t stream) {
  const float* x = (const float*)d_in[0];
  const int* ei = (const int*)d_in[1];
  const float* eattr = (const float*)d_in[2];
  const int* batch = (const int*)d_in[3];
  const float* Wf = (const float*)d_in[4];
  const float* bf = (const float*)d_in[5];
  const float* Ws = (const float*)d_in[6];
  const float* bs = (const float*)d_in[7];
  const float* bn_w = (const float*)d_in[8];
  const float* bn_b = (const float*)d_in[9];
  const float* ln_w = (const float*)d_in[10];
  const float* ln_b = (const float*)d_in[11];
  const float* Wl = (const float*)d_in[12];
  const float* bl = (const float*)d_in[13];
  const float* w4 = (const float*)d_in[14];
  const float* b4 = (const float*)d_in[15];

  const int N = in_sizes[0] / 64;
  const int E = in_sizes[2] / 32;
  const int G = 512;
  const int NB = (N + 255) / 256;
  const int T16 = (E + 15) / 16;
  const int NCV = (N * 8 + 255) / 256;
  const int NH = (E + 255) / 256;

  // Workspace layout (floats; each chunk multiple of 4 => 16B alignment).
  float* ws = (float*)d_ws;
  float* agg = ws;                                   // N*64  [zeroed]
  float* stats = agg + (size_t)N * 64;               // 320   [zeroed]
  float* add_pool = stats + 320;                     // G*64  [zeroed]
  float* counts = add_pool + (size_t)G * 64;         // G     [zeroed]
  int* deg = (int*)(counts + G);                     // N     [zeroed]
  int* cursor = deg + N;                             // N
  int* bsum = cursor + N;                            // 256
  int* bpre = bsum + 256;                            // 256
  unsigned short* Bfrag = (unsigned short*)(bpre + 256);   // 12288 ush (24KB)
  unsigned short* Bfrag2 = Bfrag + 12288;                  // 8192 ush (16KB)
  unsigned short* xbf = Bfrag2 + 8192;                     // N*64 ush
  unsigned* Pd = (unsigned*)(xbf + (size_t)N * 64);        // N*64 u32
  int2* epair2 = (int2*)(Pd + (size_t)N * 64);             // T16*16 int2

  size_t zeroFloats = (size_t)N * 64 + 320 + (size_t)G * 64 + G + N;
  hipMemsetAsync(agg, 0, zeroFloats * sizeof(float), stream);
  const int padE = T16 * 16 - E;
  if (padE > 0) hipMemsetAsync(epair2 + E, 0xFF, (size_t)padE * 8, stream);

  prep_kernel<<<NCV + 10 + NH, 256, 0, stream>>>(x, Wf, Ws, ei, xbf, Bfrag,
                                                 Bfrag2, deg, NCV, N * 8, E);
  node_mfma<<<(N + 63) / 64, 256, 0, stream>>>(xbf, Bfrag2, bf, bs, Pd, N);
  scan_a<<<NB, 256, 0, stream>>>(deg, bsum, N);
  scan_b<<<1, 256, 0, stream>>>(bsum, bpre, NB);
  scan_c<<<NB, 256, 0, stream>>>(deg, bpre, cursor, N);
  scatter_kernel<<<NH, 256, 0, stream>>>(ei, cursor, epair2, E);
  edge_fused<<<1024, 256, 0, stream>>>(epair2, eattr, xbf, Bfrag, Pd, agg, T16,
                                       N, E);
  stats_kernel<<<512, 256, 0, stream>>>(agg, x, stats, N);
  const int chunk = (N + 511) / 512;
  node_finish<<<512, 256, 0, stream>>>(stats, bn_w, bn_b, agg, x, batch, ln_w,
                                       ln_b, add_pool, counts, N, chunk);
  graph_out<<<1, 1024, 0, stream>>>(add_pool, counts, Wl, bl, w4, b4,
                                    (float*)d_out, G);
}